// Round 4
// baseline (328.308 us; speedup 1.0000x reference)
//
#include <hip/hip_runtime.h>
#include <hip/hip_bf16.h>
#include <hip/hip_cooperative_groups.h>

namespace cg = cooperative_groups;

#define B_ 4
#define N_ 4096
#define L_ 4104
#define D_ 512
#define BK 64
#define NF 210     // monomials of degree <=6 in 4 vars
#define ZCH 36     // zphi chunk length (multiple of 12 -> aligned pooling windows)
#define ZCHUNKS 114  // 114*36 == 4104 == L_
#define PST 37     // P LDS row stride (coprime with 32 -> conflict-free column reads)
#define GRID 512   // 2 blocks/CU guaranteed co-resident (LDS 50K, launch_bounds(256,2))

typedef __attribute__((ext_vector_type(8))) short bf16x8;
typedef __attribute__((ext_vector_type(4))) float f32x4;

struct GS { __hip_bfloat16 As[2][64 * BK]; __hip_bfloat16 Bs[2][128 * BK]; float cwS[512]; };
struct ZS { float twj[ZCH]; float P[32][PST]; unsigned pkS[NF]; int tokS[ZCH + 3]; };
struct FS { float wgtS[48]; float tbS[12]; float Pr[12][33]; float Zl[NF * 5];
            unsigned pkS[NF]; float cfS[NF]; int tokS[16]; };

// helper: 4-way softmax from a t-window in LDS
__device__ __forceinline__ float4 softmax4(const float* __restrict__ tw, int base,
                                           int i, float bb) {
  const float s0 = tw[i - base] + bb;
  const int j2 = i & ~1;
  const float s1 = (tw[j2 - base] + tw[j2 + 1 - base]) * 0.5f + bb;
  const int j3 = (i / 3) * 3;
  const float s2 = (tw[j3 - base] + tw[j3 + 1 - base] + tw[j3 + 2 - base]) * (1.f / 3.f) + bb;
  const int j4 = i & ~3;
  const float s3 = (tw[j4 - base] + tw[j4 + 1 - base] + tw[j4 + 2 - base] + tw[j4 + 3 - base]) * 0.25f + bb;
  const float m = fmaxf(fmaxf(s0, s1), fmaxf(s2, s3));
  const float e0 = __expf(s0 - m), e1 = __expf(s1 - m), e2 = __expf(s2 - m), e3 = __expf(s3 - m);
  const float inv = 1.f / (e0 + e1 + e2 + e3);
  return make_float4(e0 * inv, e1 * inv, e2 * inv, e3 * inv);
}

__global__ __launch_bounds__(256, 2) void k_all(const int* __restrict__ x,
    const float* __restrict__ emb, const float* __restrict__ cwp,
    const float* __restrict__ cb, const float* __restrict__ pw,
    const float* __restrict__ pb, const float* __restrict__ sw,
    const float* __restrict__ sb,
    float* __restrict__ G, float* __restrict__ biasp,
    unsigned* __restrict__ featPk, float* __restrict__ featCf,
    float* __restrict__ Zg, float* __restrict__ TS, float* __restrict__ c0g,
    float* __restrict__ out) {
  __shared__ __align__(16) union { GS g; ZS z; FS f; } u;
  __shared__ float red[4];
  cg::grid_group grid = cg::this_grid();
  const int bx = blockIdx.x;
  const int t = threadIdx.x;

  // ================= Stage A: GEMM G, bias', feat table, zero Zg =================
  if (bx < 64) {
    const int w = t >> 6, l = t & 63;
    const int m0 = (bx & 3) * 64;          // token tile
    const int n0 = ((bx >> 2) & 3) * 128;  // output-channel tile
    const int kp = bx >> 4;                // conv tap 0..3
    const int quad = l >> 4, r16 = l & 15;
    const int wc = w * 32;
    auto& As = u.g.As;
    auto& Bs = u.g.Bs;
    float* cwS = u.g.cwS;

    cwS[t]       = cwp[t * 4 + kp];
    cwS[t + 256] = cwp[(t + 256) * 4 + kp];

    f32x4 acc[4][2];
#pragma unroll
    for (int a = 0; a < 4; ++a)
#pragma unroll
      for (int bq = 0; bq < 2; ++bq) acc[a][bq] = (f32x4){0.f, 0.f, 0.f, 0.f};

    const int ra = t >> 2, ga0 = (t & 3) * 2;
    const int rb = t >> 1, gb0 = (t & 1) * 4;

#define STAGEG(buf, kb)                                                          \
  _Pragma("unroll")                                                              \
  for (int gi = 0; gi < 2; ++gi) {                                               \
    const int g = ga0 + gi;                                                      \
    const int c0 = (kb) + g * 8;                                                 \
    const float4 a0 = *(const float4*)(emb + (size_t)(m0 + ra) * 512 + c0);      \
    const float4 a1 = *(const float4*)(emb + (size_t)(m0 + ra) * 512 + c0 + 4);  \
    const float4 w0 = *(const float4*)(cwS + c0);                                \
    const float4 w1 = *(const float4*)(cwS + c0 + 4);                            \
    union { __hip_bfloat16 q[8]; bf16x8 v; } ua;                                 \
    ua.q[0] = __float2bfloat16(a0.x * w0.x); ua.q[1] = __float2bfloat16(a0.y * w0.y); \
    ua.q[2] = __float2bfloat16(a0.z * w0.z); ua.q[3] = __float2bfloat16(a0.w * w0.w); \
    ua.q[4] = __float2bfloat16(a1.x * w1.x); ua.q[5] = __float2bfloat16(a1.y * w1.y); \
    ua.q[6] = __float2bfloat16(a1.z * w1.z); ua.q[7] = __float2bfloat16(a1.w * w1.w); \
    *(bf16x8*)(&As[buf][ra * BK + ((g ^ (ra & 7)) * 8)]) = ua.v;                 \
  }                                                                              \
  _Pragma("unroll")                                                              \
  for (int gi = 0; gi < 4; ++gi) {                                               \
    const int g = gb0 + gi;                                                      \
    const int c0 = (kb) + g * 8;                                                 \
    const float4 b0 = *(const float4*)(pw + (size_t)(n0 + rb) * 512 + c0);       \
    const float4 b1 = *(const float4*)(pw + (size_t)(n0 + rb) * 512 + c0 + 4);   \
    union { __hip_bfloat16 q[8]; bf16x8 v; } ub;                                 \
    ub.q[0] = __float2bfloat16(b0.x); ub.q[1] = __float2bfloat16(b0.y);          \
    ub.q[2] = __float2bfloat16(b0.z); ub.q[3] = __float2bfloat16(b0.w);          \
    ub.q[4] = __float2bfloat16(b1.x); ub.q[5] = __float2bfloat16(b1.y);          \
    ub.q[6] = __float2bfloat16(b1.z); ub.q[7] = __float2bfloat16(b1.w);          \
    *(bf16x8*)(&Bs[buf][rb * BK + ((g ^ (rb & 7)) * 8)]) = ub.v;                 \
  }

    __syncthreads();        // cwS ready
    STAGEG(0, 0)
    __syncthreads();

#pragma unroll 1
    for (int kt = 0; kt < 8; ++kt) {
      const int cur = kt & 1;
      if (kt < 7) { STAGEG(1 - cur, (kt + 1) * BK) }
#pragma unroll
      for (int kk = 0; kk < 2; ++kk) {
        const int col_e = (kk * 32 + quad * 8) ^ ((r16 & 7) * 8);
        bf16x8 af[4], bfr[2];
#pragma unroll
        for (int ti = 0; ti < 4; ++ti)
          af[ti] = *(const bf16x8*)(&As[cur][(ti * 16 + r16) * BK + col_e]);
#pragma unroll
        for (int tj = 0; tj < 2; ++tj)
          bfr[tj] = *(const bf16x8*)(&Bs[cur][(wc + tj * 16 + r16) * BK + col_e]);
#pragma unroll
        for (int ti = 0; ti < 4; ++ti)
#pragma unroll
          for (int tj = 0; tj < 2; ++tj)
            acc[ti][tj] = __builtin_amdgcn_mfma_f32_16x16x32_bf16(af[ti], bfr[tj], acc[ti][tj], 0, 0, 0);
      }
      __syncthreads();
    }
#undef STAGEG

#pragma unroll
    for (int ti = 0; ti < 4; ++ti) {
      const int gi0 = m0 + ti * 16 + quad * 4;
#pragma unroll
      for (int tj = 0; tj < 2; ++tj) {
        const int go = n0 + wc + tj * 16 + r16;
#pragma unroll
        for (int r = 0; r < 4; ++r)
          G[((size_t)kp * 256 + gi0 + r) * 512 + go] = acc[ti][tj][r];
      }
    }
  } else if (bx < 96) {                  // bias': wave-parallel, no barriers
    const int w = t >> 6, l = t & 63;
    const float4 cb0 = *(const float4*)(cb + l * 8);
    const float4 cb1 = *(const float4*)(cb + l * 8 + 4);
#pragma unroll
    for (int i = 0; i < 4; ++i) {
      const int o = (bx - 64) * 16 + w * 4 + i;
      const float4 w0 = *(const float4*)(pw + (size_t)o * 512 + l * 8);
      const float4 w1 = *(const float4*)(pw + (size_t)o * 512 + l * 8 + 4);
      float s = w0.x * cb0.x + w0.y * cb0.y + w0.z * cb0.z + w0.w * cb0.w
              + w1.x * cb1.x + w1.y * cb1.y + w1.z * cb1.z + w1.w * cb1.w;
#pragma unroll
      for (int off = 32; off > 0; off >>= 1) s += __shfl_xor(s, off);
      if (l == 0) biasp[o] = s + pb[o];
    }
  } else if (bx == 96) {                 // feature table + zero moment buffer
    for (int zi = t; zi < B_ * NF * 5; zi += 256) Zg[zi] = 0.f;
    if (t < NF) {
      int idx = 0, mp = 0, mq = 0, mr = 0, ms = 0;
      for (int m = 0; m <= 6; ++m)
        for (int p = m; p >= 0; --p)
          for (int q = m - p; q >= 0; --q)
            for (int r = m - p - q; r >= 0; --r) {
              const int s4 = m - p - q - r;
              if (idx == t) { mp = p; mq = q; mr = r; ms = s4; }
              ++idx;
            }
      featPk[t] = (unsigned)mp | ((unsigned)mq << 8) | ((unsigned)mr << 16) | ((unsigned)ms << 24);
      const float invf[7] = {1.f, 1.f, 0.5f, 1.f/6.f, 1.f/24.f, 1.f/120.f, 1.f/720.f};
      featCf[t] = invf[mp] * invf[mq] * invf[mr] * invf[ms];
    }
  }

  grid.sync();

  // ================= Stage B: TS[row] = G[row,:].sw (wave per row), c0 ===========
  if (bx < 256) {
    const int w = t >> 6, l = t & 63;
    const int row = bx * 4 + w;
    const float4 s0 = *(const float4*)(sw + l * 8);
    const float4 s1 = *(const float4*)(sw + l * 8 + 4);
    const float4 g0 = *(const float4*)(G + (size_t)row * 512 + l * 8);
    const float4 g1 = *(const float4*)(G + (size_t)row * 512 + l * 8 + 4);
    float s = g0.x * s0.x + g0.y * s0.y + g0.z * s0.z + g0.w * s0.w
            + g1.x * s1.x + g1.y * s1.y + g1.z * s1.z + g1.w * s1.w;
#pragma unroll
    for (int off = 32; off > 0; off >>= 1) s += __shfl_xor(s, off);
    if (l == 0) TS[row] = s;
  } else if (bx == 256) {                // c0 = biasp . sw
    const int w = t >> 6, l = t & 63;
    const float2 a = *(const float2*)(biasp + t * 2);
    const float2 b = *(const float2*)(sw + t * 2);
    float s = a.x * b.x + a.y * b.y;
#pragma unroll
    for (int off = 32; off > 0; off >>= 1) s += __shfl_xor(s, off);
    if (l == 0) red[w] = s;
    __syncthreads();
    if (t == 0) c0g[0] = red[0] + red[1] + red[2] + red[3];
  }

  grid.sync();

  // ================= Stage C: j-side moments Z ===================================
  if (bx < B_ * ZCHUNKS) {
    const int b = bx / ZCHUNKS, jc = bx % ZCHUNKS;
    const int j0 = jc * ZCH;
    float* twj = u.z.twj;
    float (&P)[32][PST] = u.z.P;
    unsigned* pkS = u.z.pkS;
    int* tokS = u.z.tokS;
    if (t < NF) pkS[t] = featPk[t];
    if (t < ZCH + 3) {
      const int j = j0 + t;
      tokS[t] = (j < N_) ? x[b * N_ + j] : -1;
    }
    __syncthreads();
    if (t < ZCH) {
      float tv = 0.f;
      if (j0 + t < N_) {
        tv = c0g[0];
#pragma unroll
        for (int k = 0; k < 4; ++k) {
          const int tk = tokS[t + k];
          if (tk >= 0) tv += TS[k * 256 + tk];
        }
      }
      twj[t] = tv;
    }
    __syncthreads();
    const float bb = sb[0];
    if (t < ZCH) {
      const float4 s = softmax4(twj, j0, j0 + t, bb);
      P[0][t] = 1.f; P[8][t] = 1.f; P[16][t] = 1.f; P[24][t] = 1.f;
      float va = 1.f, vb = 1.f, vc = 1.f, vd = 1.f;
#pragma unroll
      for (int e = 1; e < 8; ++e) {
        va *= s.x; vb *= s.y; vc *= s.z; vd *= s.w;
        P[e][t] = va; P[8 + e][t] = vb; P[16 + e][t] = vc; P[24 + e][t] = vd;
      }
    }
    __syncthreads();
    if (t < NF) {
      const unsigned pk = pkS[t];
      const int p = pk & 255, q = (pk >> 8) & 255, r = (pk >> 16) & 255, s4 = pk >> 24;
      const float* Ra0 = &P[p][0];       const float* Ra1 = &P[p + 1][0];
      const float* Rb0 = &P[8 + q][0];   const float* Rb1 = &P[8 + q + 1][0];
      const float* Rc0 = &P[16 + r][0];  const float* Rc1 = &P[16 + r + 1][0];
      const float* Rd0 = &P[24 + s4][0]; const float* Rd1 = &P[24 + s4 + 1][0];
      float z0 = 0.f, z1 = 0.f, z2 = 0.f, z3 = 0.f, z4 = 0.f;
#pragma unroll 4
      for (int jj = 0; jj < ZCH; ++jj) {
        const float pa0 = Ra0[jj], pa1 = Ra1[jj];
        const float pb0 = Rb0[jj], pb1 = Rb1[jj];
        const float pc0 = Rc0[jj], pc1 = Rc1[jj];
        const float pd0 = Rd0[jj], pd1 = Rd1[jj];
        const float cd = pc0 * pd0, ab = pa0 * pb0;
        z4 += pa0 * (pb0 * cd);
        z0 += pa1 * (pb0 * cd);
        z1 += pb1 * (pa0 * cd);
        z2 += pc1 * (ab * pd0);
        z3 += pd1 * (ab * pc0);
      }
      float* zb = Zg + (size_t)(b * NF + t) * 5;
      atomicAdd(zb + 0, z0); atomicAdd(zb + 1, z1); atomicAdd(zb + 2, z2);
      atomicAdd(zb + 3, z3); atomicAdd(zb + 4, z4);
    }
  }

  grid.sync();

  // ================= Stage D: fuse tiles (3 per block max) =======================
  {
    const int d = t * 2;
    if (t < NF) { u.f.pkS[t] = featPk[t]; u.f.cfS[t] = featCf[t]; }
    for (int tile = bx; tile < B_ * 342; tile += GRID) {
      const int b = tile / 342, j12 = tile % 342;
      const int r0 = 12 * j12;
      for (int i2 = t; i2 < NF * 5; i2 += 256) u.f.Zl[i2] = Zg[(size_t)b * NF * 5 + i2];
      if (t < 15) {
        const int j = r0 + t;
        u.f.tokS[t] = (j < N_) ? x[b * N_ + j] : -1;
      }
      __syncthreads();

      // h rows via direct G gather (L2-resident); t-scores via TS lookup
      const float2 bp = *(const float2*)(biasp + d);
      float2 hv[12];
#pragma unroll
      for (int q = 0; q < 12; ++q) {
        float2 a = make_float2(0.f, 0.f);
        if (r0 + q < N_) {
          a = bp;
#pragma unroll
          for (int k = 0; k < 4; ++k) {
            const int tk = u.f.tokS[q + k];
            if (tk >= 0) {
              const float2 g = *(const float2*)(G + ((size_t)k * 256 + tk) * 512 + d);
              a.x += g.x; a.y += g.y;
            }
          }
        }
        hv[q] = a;
      }

      if (t < 12) {
        float tv = 0.f;
        if (r0 + t < N_) {
          tv = c0g[0];
#pragma unroll
          for (int k = 0; k < 4; ++k) {
            const int tk = u.f.tokS[t + k];
            if (tk >= 0) tv += TS[k * 256 + tk];
          }
        }
        u.f.tbS[t] = tv;
      }
      __syncthreads();
      if (t < 12) {                      // powers of s_i for this tile's 12 rows
        const float4 s = softmax4(u.f.tbS, r0, r0 + t, sb[0]);
        float* p = &u.f.Pr[t][0];
        float va = 1.f, vb = 1.f, vc = 1.f, vd = 1.f;
        p[0] = 1.f; p[8] = 1.f; p[16] = 1.f; p[24] = 1.f;
#pragma unroll
        for (int e = 1; e < 8; ++e) {
          va *= s.x; vb *= s.y; vc *= s.z; vd *= s.w;
          p[e] = va; p[8 + e] = vb; p[16 + e] = vc; p[24 + e] = vd;
        }
      }
      __syncthreads();
      if (t < 192) {                     // 16 lanes per row evaluate phi . Z
        const int row = t >> 4, fi = t & 15;
        float n0 = 0.f, n1 = 0.f, n2 = 0.f, n3 = 0.f, dn = 0.f;
        const float* pr = &u.f.Pr[row][0];
        for (int f = fi; f < NF; f += 16) {
          const unsigned pk = u.f.pkS[f];
          const float val = u.f.cfS[f] * pr[pk & 255] * pr[8 + ((pk >> 8) & 255)]
                                       * pr[16 + ((pk >> 16) & 255)] * pr[24 + (pk >> 24)];
          const float* z = &u.f.Zl[f * 5];
          n0 += val * z[0]; n1 += val * z[1]; n2 += val * z[2]; n3 += val * z[3];
          dn += val * z[4];
        }
#pragma unroll
        for (int m = 8; m >= 1; m >>= 1) {
          n0 += __shfl_xor(n0, m); n1 += __shfl_xor(n1, m); n2 += __shfl_xor(n2, m);
          n3 += __shfl_xor(n3, m); dn += __shfl_xor(dn, m);
        }
        if (fi == 0) {
          const float inv = 1.f / dn;
          u.f.wgtS[row * 4 + 0] = n0 * inv; u.f.wgtS[row * 4 + 1] = n1 * inv;
          u.f.wgtS[row * 4 + 2] = n2 * inv; u.f.wgtS[row * 4 + 3] = n3 * inv;
        }
      }
      __syncthreads();

      float2 p2[6], p3[4], p4[3];
#pragma unroll
      for (int g = 0; g < 6; ++g) {
        p2[g].x = (hv[2 * g].x + hv[2 * g + 1].x) * 0.5f;
        p2[g].y = (hv[2 * g].y + hv[2 * g + 1].y) * 0.5f;
      }
#pragma unroll
      for (int g = 0; g < 4; ++g) {
        p3[g].x = (hv[3 * g].x + hv[3 * g + 1].x + hv[3 * g + 2].x) * (1.f / 3.f);
        p3[g].y = (hv[3 * g].y + hv[3 * g + 1].y + hv[3 * g + 2].y) * (1.f / 3.f);
      }
#pragma unroll
      for (int g = 0; g < 3; ++g) {
        p4[g].x = (hv[4 * g].x + hv[4 * g + 1].x + hv[4 * g + 2].x + hv[4 * g + 3].x) * 0.25f;
        p4[g].y = (hv[4 * g].y + hv[4 * g + 1].y + hv[4 * g + 2].y + hv[4 * g + 3].y) * 0.25f;
      }

#pragma unroll
      for (int o = 0; o < 3; ++o) {
        const int orow = j12 * 3 + o;
        if (orow < 1024) {
          float ox = 0.f, oy = 0.f;
#pragma unroll
          for (int rr = 0; rr < 4; ++rr) {
            const int r = 4 * o + rr;
            const float4 wv = make_float4(u.f.wgtS[r * 4], u.f.wgtS[r * 4 + 1],
                                          u.f.wgtS[r * 4 + 2], u.f.wgtS[r * 4 + 3]);
            const float2 p1 = hv[r];
            const float2 q2 = p2[r >> 1];
            const float2 q3 = p3[r / 3];
            const float2 q4 = p4[o];
            ox += wv.x * p1.x + wv.y * q2.x + wv.z * q3.x + wv.w * q4.x;
            oy += wv.x * p1.y + wv.y * q2.y + wv.z * q3.y + wv.w * q4.y;
          }
          float2 ov; ov.x = ox * 0.25f; ov.y = oy * 0.25f;
          *(float2*)(out + (size_t)(b * 1024 + orow) * D_ + d) = ov;
        }
      }
      __syncthreads();   // LDS reuse across tiles
    }
  }
}

extern "C" void kernel_launch(void* const* d_in, const int* in_sizes, int n_in,
                              void* d_out, int out_size, void* d_ws, size_t ws_size,
                              hipStream_t stream) {
  const int*   x       = (const int*)d_in[0];
  const float* emb     = (const float*)d_in[1];
  const float* conv_w  = (const float*)d_in[2];
  const float* conv_b  = (const float*)d_in[3];
  const float* proj_w  = (const float*)d_in[4];
  const float* proj_b  = (const float*)d_in[5];
  const float* score_w = (const float*)d_in[6];
  const float* score_b = (const float*)d_in[7];
  float* out = (float*)d_out;

  char* ws = (char*)d_ws;
  size_t off = 0;
  float*    G      = (float*)(ws + off); off += (size_t)4 * 256 * 512 * 4;  // 2 MB
  float*    bias   = (float*)(ws + off); off += (size_t)512 * 4;
  float*    Zg     = (float*)(ws + off); off += (size_t)B_ * NF * 5 * 4;    // 16.8 KB
  unsigned* featPk = (unsigned*)(ws + off); off += (size_t)1024;
  float*    featCf = (float*)(ws + off); off += (size_t)1024;
  float*    TS     = (float*)(ws + off); off += (size_t)1024 * 4;           // 4 KB
  float*    c0     = (float*)(ws + off); off += (size_t)16;
  (void)in_sizes; (void)n_in; (void)out_size; (void)ws_size;

  void* args[] = { (void*)&x, (void*)&emb, (void*)&conv_w, (void*)&conv_b,
                   (void*)&proj_w, (void*)&proj_b, (void*)&score_w, (void*)&score_b,
                   (void*)&G, (void*)&bias, (void*)&featPk, (void*)&featCf,
                   (void*)&Zg, (void*)&TS, (void*)&c0, (void*)&out };
  hipLaunchCooperativeKernel((void*)k_all, dim3(GRID), dim3(256), args, 0, stream);
}

// Round 5
// 140.989 us; speedup vs baseline: 2.3286x; 2.3286x over previous
//
#include <hip/hip_runtime.h>
#include <hip/hip_bf16.h>

#define B_ 4
#define N_ 4096
#define L_ 4104
#define D_ 512
#define BK 64
#define NF 210     // monomials of degree <=6 in 4 vars
#define ZCH 36     // zphi chunk length (multiple of 12 -> aligned pooling windows)
#define ZCHUNKS 114  // 114*36 == 4104 == L_
#define PST 37     // P LDS row stride (coprime with 32 -> conflict-free column reads)

typedef __attribute__((ext_vector_type(8))) short bf16x8;
typedef __attribute__((ext_vector_type(4))) float f32x4;

struct GemmS { __hip_bfloat16 As[2][64 * BK]; __hip_bfloat16 Bs[2][128 * BK]; float cwS[512]; };
struct TsS   { float swS[512]; float uPart[4][512]; float vkS[512]; };

// ---------------- K0: GEMM G + bias' + feat table + TS (emb path, concurrent) --------
__global__ __launch_bounds__(256) void k_g(const float* __restrict__ emb,
    const float* __restrict__ pw, const float* __restrict__ cwp,
    const float* __restrict__ cb, const float* __restrict__ pb,
    const float* __restrict__ sw,
    float* __restrict__ G, float* __restrict__ biasp,
    unsigned* __restrict__ featPk, float* __restrict__ featCf,
    float* __restrict__ Zg, float* __restrict__ TS, float* __restrict__ c0g) {
  __shared__ __align__(16) union { GemmS g; TsS ts; } u;
  __shared__ float red[4];
  const int bx = blockIdx.x;
  const int t = threadIdx.x;
  const int w = t >> 6, l = t & 63;

  if (bx >= 97) {                        // ---- TS blocks: one per conv tap, no G dep
    const int kp = bx - 97;
    float* swS = u.ts.swS;
    float* vkS = u.ts.vkS;
    swS[t] = sw[t]; swS[t + 256] = sw[t + 256];
    __syncthreads();
    // u[c] = sum_o sw[o]*W[o,c]; rows split across 4 waves (128 rows each)
    const int c8 = l * 8;
    float4 acc0 = {0.f, 0.f, 0.f, 0.f}, acc1 = {0.f, 0.f, 0.f, 0.f};
    const int o0 = w * 128;
#pragma unroll 4
    for (int oo = 0; oo < 128; ++oo) {
      const int o = o0 + oo;
      const float so = swS[o];
      const float4 w0 = *(const float4*)(pw + (size_t)o * 512 + c8);
      const float4 w1 = *(const float4*)(pw + (size_t)o * 512 + c8 + 4);
      acc0.x += so * w0.x; acc0.y += so * w0.y; acc0.z += so * w0.z; acc0.w += so * w0.w;
      acc1.x += so * w1.x; acc1.y += so * w1.y; acc1.z += so * w1.z; acc1.w += so * w1.w;
    }
    *(float4*)(&u.ts.uPart[w][c8])     = acc0;
    *(float4*)(&u.ts.uPart[w][c8 + 4]) = acc1;
    __syncthreads();
    const int c2 = t * 2;
    const float uu0 = u.ts.uPart[0][c2] + u.ts.uPart[1][c2]
                    + u.ts.uPart[2][c2] + u.ts.uPart[3][c2];
    const float uu1 = u.ts.uPart[0][c2 + 1] + u.ts.uPart[1][c2 + 1]
                    + u.ts.uPart[2][c2 + 1] + u.ts.uPart[3][c2 + 1];
    vkS[c2]     = uu0 * cwp[c2 * 4 + kp];
    vkS[c2 + 1] = uu1 * cwp[(c2 + 1) * 4 + kp];
    if (kp == 0) {                       // c0 = cb.u + pb.sw
      float part = cb[c2] * uu0 + cb[c2 + 1] * uu1
                 + pb[c2] * swS[c2] + pb[c2 + 1] * swS[c2 + 1];
#pragma unroll
      for (int m = 32; m >= 1; m >>= 1) part += __shfl_xor(part, m);
      if (l == 0) red[w] = part;
    }
    __syncthreads();                     // vkS (and red) ready
    if (kp == 0 && t == 0) c0g[0] = red[0] + red[1] + red[2] + red[3];
    const int r16 = t & 15, tg = t >> 4; // 16 lanes per token
    for (int tok0 = 0; tok0 < 256; tok0 += 16) {
      const int tok = tok0 + tg;
      float dot = 0.f;
#pragma unroll
      for (int it = 0; it < 8; ++it) {
        const int c = it * 64 + r16 * 4;
        const float4 e4 = *(const float4*)(emb + (size_t)tok * 512 + c);
        const float4 v4 = *(const float4*)(vkS + c);
        dot += e4.x * v4.x + e4.y * v4.y + e4.z * v4.z + e4.w * v4.w;
      }
#pragma unroll
      for (int m = 8; m >= 1; m >>= 1) dot += __shfl_xor(dot, m);
      if (r16 == 0) TS[kp * 256 + tok] = dot;
    }
    return;
  }
  if (bx == 96) {                        // ---- feature table + zero moment buffer
    for (int zi = t; zi < B_ * NF * 5; zi += 256) Zg[zi] = 0.f;
    if (t < NF) {
      int idx = 0, mp = 0, mq = 0, mr = 0, ms = 0;
      for (int m = 0; m <= 6; ++m)
        for (int p = m; p >= 0; --p)
          for (int q = m - p; q >= 0; --q)
            for (int r = m - p - q; r >= 0; --r) {
              const int s4 = m - p - q - r;
              if (idx == t) { mp = p; mq = q; mr = r; ms = s4; }
              ++idx;
            }
      featPk[t] = (unsigned)mp | ((unsigned)mq << 8) | ((unsigned)mr << 16) | ((unsigned)ms << 24);
      const float invf[7] = {1.f, 1.f, 0.5f, 1.f/6.f, 1.f/24.f, 1.f/120.f, 1.f/720.f};
      featCf[t] = invf[mp] * invf[mq] * invf[mr] * invf[ms];
    }
    return;
  }
  if (bx >= 64) {                        // ---- bias': wave-parallel, barrier-free
    const float4 cb0 = *(const float4*)(cb + l * 8);
    const float4 cb1 = *(const float4*)(cb + l * 8 + 4);
#pragma unroll
    for (int i = 0; i < 4; ++i) {
      const int o = (bx - 64) * 16 + w * 4 + i;
      const float4 w0 = *(const float4*)(pw + (size_t)o * 512 + l * 8);
      const float4 w1 = *(const float4*)(pw + (size_t)o * 512 + l * 8 + 4);
      float s = w0.x * cb0.x + w0.y * cb0.y + w0.z * cb0.z + w0.w * cb0.w
              + w1.x * cb1.x + w1.y * cb1.y + w1.z * cb1.z + w1.w * cb1.w;
#pragma unroll
      for (int off = 32; off > 0; off >>= 1) s += __shfl_xor(s, off);
      if (l == 0) biasp[o] = s + pb[o];
    }
    return;
  }

  // ---- GEMM: G_k = bf16(emb*cw_k) @ bf16(W)^T
  const int m0 = (bx & 3) * 64;          // token tile
  const int n0 = ((bx >> 2) & 3) * 128;  // output-channel tile
  const int kp = bx >> 4;                // conv tap 0..3
  const int quad = l >> 4, r16 = l & 15;
  const int wc = w * 32;
  auto& As = u.g.As;
  auto& Bs = u.g.Bs;
  float* cwS = u.g.cwS;

  cwS[t]       = cwp[t * 4 + kp];
  cwS[t + 256] = cwp[(t + 256) * 4 + kp];

  f32x4 acc[4][2];
#pragma unroll
  for (int a = 0; a < 4; ++a)
#pragma unroll
    for (int bq = 0; bq < 2; ++bq) acc[a][bq] = (f32x4){0.f, 0.f, 0.f, 0.f};

  const int ra = t >> 2, ga0 = (t & 3) * 2;
  const int rb = t >> 1, gb0 = (t & 1) * 4;

#define STAGEG(buf, kb)                                                          \
  _Pragma("unroll")                                                              \
  for (int gi = 0; gi < 2; ++gi) {                                               \
    const int g = ga0 + gi;                                                      \
    const int c0 = (kb) + g * 8;                                                 \
    const float4 a0 = *(const float4*)(emb + (size_t)(m0 + ra) * 512 + c0);      \
    const float4 a1 = *(const float4*)(emb + (size_t)(m0 + ra) * 512 + c0 + 4);  \
    const float4 w0 = *(const float4*)(cwS + c0);                                \
    const float4 w1 = *(const float4*)(cwS + c0 + 4);                            \
    union { __hip_bfloat16 q[8]; bf16x8 v; } ua;                                 \
    ua.q[0] = __float2bfloat16(a0.x * w0.x); ua.q[1] = __float2bfloat16(a0.y * w0.y); \
    ua.q[2] = __float2bfloat16(a0.z * w0.z); ua.q[3] = __float2bfloat16(a0.w * w0.w); \
    ua.q[4] = __float2bfloat16(a1.x * w1.x); ua.q[5] = __float2bfloat16(a1.y * w1.y); \
    ua.q[6] = __float2bfloat16(a1.z * w1.z); ua.q[7] = __float2bfloat16(a1.w * w1.w); \
    *(bf16x8*)(&As[buf][ra * BK + ((g ^ (ra & 7)) * 8)]) = ua.v;                 \
  }                                                                              \
  _Pragma("unroll")                                                              \
  for (int gi = 0; gi < 4; ++gi) {                                               \
    const int g = gb0 + gi;                                                      \
    const int c0 = (kb) + g * 8;                                                 \
    const float4 b0 = *(const float4*)(pw + (size_t)(n0 + rb) * 512 + c0);       \
    const float4 b1 = *(const float4*)(pw + (size_t)(n0 + rb) * 512 + c0 + 4);   \
    union { __hip_bfloat16 q[8]; bf16x8 v; } ub;                                 \
    ub.q[0] = __float2bfloat16(b0.x); ub.q[1] = __float2bfloat16(b0.y);          \
    ub.q[2] = __float2bfloat16(b0.z); ub.q[3] = __float2bfloat16(b0.w);          \
    ub.q[4] = __float2bfloat16(b1.x); ub.q[5] = __float2bfloat16(b1.y);          \
    ub.q[6] = __float2bfloat16(b1.z); ub.q[7] = __float2bfloat16(b1.w);          \
    *(bf16x8*)(&Bs[buf][rb * BK + ((g ^ (rb & 7)) * 8)]) = ub.v;                 \
  }

  __syncthreads();        // cwS ready
  STAGEG(0, 0)
  __syncthreads();

#pragma unroll 1
  for (int kt = 0; kt < 8; ++kt) {
    const int cur = kt & 1;
    if (kt < 7) { STAGEG(1 - cur, (kt + 1) * BK) }
#pragma unroll
    for (int kk = 0; kk < 2; ++kk) {
      const int col_e = (kk * 32 + quad * 8) ^ ((r16 & 7) * 8);
      bf16x8 af[4], bfr[2];
#pragma unroll
      for (int ti = 0; ti < 4; ++ti)
        af[ti] = *(const bf16x8*)(&As[cur][(ti * 16 + r16) * BK + col_e]);
#pragma unroll
      for (int tj = 0; tj < 2; ++tj)
        bfr[tj] = *(const bf16x8*)(&Bs[cur][(wc + tj * 16 + r16) * BK + col_e]);
#pragma unroll
      for (int ti = 0; ti < 4; ++ti)
#pragma unroll
        for (int tj = 0; tj < 2; ++tj)
          acc[ti][tj] = __builtin_amdgcn_mfma_f32_16x16x32_bf16(af[ti], bfr[tj], acc[ti][tj], 0, 0, 0);
    }
    __syncthreads();
  }
#undef STAGEG

#pragma unroll
  for (int ti = 0; ti < 4; ++ti) {
    const int gi0 = m0 + ti * 16 + quad * 4;
#pragma unroll
    for (int tj = 0; tj < 2; ++tj) {
      const int go = n0 + wc + tj * 16 + r16;
#pragma unroll
      for (int r = 0; r < 4; ++r)
        G[((size_t)kp * 256 + gi0 + r) * 512 + go] = acc[ti][tj][r];
    }
  }
}

// helper: 4-way softmax from a t-window in LDS
__device__ __forceinline__ float4 softmax4(const float* __restrict__ tw, int base,
                                           int i, float bb) {
  const float s0 = tw[i - base] + bb;
  const int j2 = i & ~1;
  const float s1 = (tw[j2 - base] + tw[j2 + 1 - base]) * 0.5f + bb;
  const int j3 = (i / 3) * 3;
  const float s2 = (tw[j3 - base] + tw[j3 + 1 - base] + tw[j3 + 2 - base]) * (1.f / 3.f) + bb;
  const int j4 = i & ~3;
  const float s3 = (tw[j4 - base] + tw[j4 + 1 - base] + tw[j4 + 2 - base] + tw[j4 + 3 - base]) * 0.25f + bb;
  const float m = fmaxf(fmaxf(s0, s1), fmaxf(s2, s3));
  const float e0 = __expf(s0 - m), e1 = __expf(s1 - m), e2 = __expf(s2 - m), e3 = __expf(s3 - m);
  const float inv = 1.f / (e0 + e1 + e2 + e3);
  return make_float4(e0 * inv, e1 * inv, e2 * inv, e3 * inv);
}

// ---------------- K1: j-side moments  Z[alpha] = sum_j s_j^alpha * [s_j;1]
// t-window from TS lookups; P transposed [32][PST] -> conflict-free column reads
__global__ __launch_bounds__(256) void k_zphi(const int* __restrict__ x,
    const float* __restrict__ TS, const float* __restrict__ c0g,
    const float* __restrict__ sb, const unsigned* __restrict__ featPk,
    float* __restrict__ Zg) {
  __shared__ float twj[ZCH];
  __shared__ float P[32][PST];
  __shared__ unsigned pkS[NF];
  __shared__ int tokS[ZCH + 3];
  const int bx = blockIdx.x;             // B_*ZCHUNKS
  const int b = bx / ZCHUNKS, jc = bx % ZCHUNKS;
  const int t = threadIdx.x;
  const int j0 = jc * ZCH;               // multiple of 12 -> pooling windows stay in-tile
  if (t < NF) pkS[t] = featPk[t];
  if (t < ZCH + 3) {
    const int j = j0 + t;
    tokS[t] = (j < N_) ? x[b * N_ + j] : -1;
  }
  __syncthreads();
  if (t < ZCH) {
    float tv = 0.f;
    if (j0 + t < N_) {
      tv = c0g[0];
#pragma unroll
      for (int k = 0; k < 4; ++k) {
        const int tk = tokS[t + k];
        if (tk >= 0) tv += TS[k * 256 + tk];
      }
    }
    twj[t] = tv;
  }
  __syncthreads();
  const float bb = sb[0];
  if (t < ZCH) {
    const float4 s = softmax4(twj, j0, j0 + t, bb);
    P[0][t] = 1.f; P[8][t] = 1.f; P[16][t] = 1.f; P[24][t] = 1.f;
    float va = 1.f, vb = 1.f, vc = 1.f, vd = 1.f;
#pragma unroll
    for (int e = 1; e < 8; ++e) {
      va *= s.x; vb *= s.y; vc *= s.z; vd *= s.w;
      P[e][t] = va; P[8 + e][t] = vb; P[16 + e][t] = vc; P[24 + e][t] = vd;
    }
  }
  __syncthreads();
  if (t < NF) {
    const unsigned pk = pkS[t];
    const int p = pk & 255, q = (pk >> 8) & 255, r = (pk >> 16) & 255, s4 = pk >> 24;
    const float* Ra0 = &P[p][0];       const float* Ra1 = &P[p + 1][0];
    const float* Rb0 = &P[8 + q][0];   const float* Rb1 = &P[8 + q + 1][0];
    const float* Rc0 = &P[16 + r][0];  const float* Rc1 = &P[16 + r + 1][0];
    const float* Rd0 = &P[24 + s4][0]; const float* Rd1 = &P[24 + s4 + 1][0];
    float z0 = 0.f, z1 = 0.f, z2 = 0.f, z3 = 0.f, z4 = 0.f;
#pragma unroll 4
    for (int jj = 0; jj < ZCH; ++jj) {
      const float pa0 = Ra0[jj], pa1 = Ra1[jj];
      const float pb0 = Rb0[jj], pb1 = Rb1[jj];
      const float pc0 = Rc0[jj], pc1 = Rc1[jj];
      const float pd0 = Rd0[jj], pd1 = Rd1[jj];
      const float cd = pc0 * pd0, ab = pa0 * pb0;
      z4 += pa0 * (pb0 * cd);
      z0 += pa1 * (pb0 * cd);
      z1 += pb1 * (pa0 * cd);
      z2 += pc1 * (ab * pd0);
      z3 += pd1 * (ab * pc0);
    }
    float* zb = Zg + (size_t)(b * NF + t) * 5;
    atomicAdd(zb + 0, z0); atomicAdd(zb + 1, z1); atomicAdd(zb + 2, z2);
    atomicAdd(zb + 3, z3); atomicAdd(zb + 4, z4);
  }
}

// ---------------- K2: 12-row tiles: wgt from phi(s_i).Z, h gathered from G, downsample
__global__ __launch_bounds__(256) void k_fuse(const int* __restrict__ x,
    const float* __restrict__ G, const float* __restrict__ biasp,
    const float* __restrict__ TS, const float* __restrict__ c0g,
    const float* __restrict__ sb, const unsigned* __restrict__ featPk,
    const float* __restrict__ featCf, const float* __restrict__ Zg,
    float* __restrict__ out) {
  __shared__ __align__(16) float4 wgtS[12];
  __shared__ float tbS[12];
  __shared__ float Pr[12][33];
  __shared__ float Zl[NF * 5];
  __shared__ unsigned pkS[NF];
  __shared__ float cfS[NF];
  __shared__ int tokS[16];
  const int bx = blockIdx.x;
  const int b = bx / 342, j12 = bx % 342;
  const int t = threadIdx.x, d = t * 2;
  const int r0 = 12 * j12;

  if (t < NF) { pkS[t] = featPk[t]; cfS[t] = featCf[t]; }
  for (int i2 = t; i2 < NF * 5; i2 += 256) Zl[i2] = Zg[(size_t)b * NF * 5 + i2];
  if (t < 15) {
    const int j = r0 + t;
    tokS[t] = (j < N_) ? x[b * N_ + j] : -1;
  }
  __syncthreads();

  // h rows via direct G gather (L2-resident); t-scores via TS lookup
  const float2 bp = *(const float2*)(biasp + d);
  float2 hv[12];
#pragma unroll
  for (int q = 0; q < 12; ++q) {
    float2 a = make_float2(0.f, 0.f);
    if (r0 + q < N_) {
      a = bp;
#pragma unroll
      for (int k = 0; k < 4; ++k) {
        const int tk = tokS[q + k];
        if (tk >= 0) {
          const float2 g = *(const float2*)(G + ((size_t)k * 256 + tk) * 512 + d);
          a.x += g.x; a.y += g.y;
        }
      }
    }
    hv[q] = a;
  }

  if (t < 12) {
    float tv = 0.f;
    if (r0 + t < N_) {
      tv = c0g[0];
#pragma unroll
      for (int k = 0; k < 4; ++k) {
        const int tk = tokS[t + k];
        if (tk >= 0) tv += TS[k * 256 + tk];
      }
    }
    tbS[t] = tv;
  }
  __syncthreads();
  if (t < 12) {                          // powers of s_i for this tile's 12 rows
    const float4 s = softmax4(tbS, r0, r0 + t, sb[0]);
    float* p = &Pr[t][0];
    float va = 1.f, vb = 1.f, vc = 1.f, vd = 1.f;
    p[0] = 1.f; p[8] = 1.f; p[16] = 1.f; p[24] = 1.f;
#pragma unroll
    for (int e = 1; e < 8; ++e) {
      va *= s.x; vb *= s.y; vc *= s.z; vd *= s.w;
      p[e] = va; p[8 + e] = vb; p[16 + e] = vc; p[24 + e] = vd;
    }
  }
  __syncthreads();
  if (t < 192) {                         // 16 lanes per row evaluate phi . Z
    const int row = t >> 4, fi = t & 15;
    float n0 = 0.f, n1 = 0.f, n2 = 0.f, n3 = 0.f, dn = 0.f;
    const float* pr = &Pr[row][0];
    for (int f = fi; f < NF; f += 16) {
      const unsigned pk = pkS[f];
      const float val = cfS[f] * pr[pk & 255] * pr[8 + ((pk >> 8) & 255)]
                                * pr[16 + ((pk >> 16) & 255)] * pr[24 + (pk >> 24)];
      const float* z = &Zl[f * 5];
      n0 += val * z[0]; n1 += val * z[1]; n2 += val * z[2]; n3 += val * z[3];
      dn += val * z[4];
    }
#pragma unroll
    for (int m = 8; m >= 1; m >>= 1) {
      n0 += __shfl_xor(n0, m); n1 += __shfl_xor(n1, m); n2 += __shfl_xor(n2, m);
      n3 += __shfl_xor(n3, m); dn += __shfl_xor(dn, m);
    }
    if (fi == 0) {
      const float inv = 1.f / dn;
      wgtS[row] = make_float4(n0 * inv, n1 * inv, n2 * inv, n3 * inv);
    }
  }
  __syncthreads();

  float2 p2[6], p3[4], p4[3];
#pragma unroll
  for (int g = 0; g < 6; ++g) {
    p2[g].x = (hv[2 * g].x + hv[2 * g + 1].x) * 0.5f;
    p2[g].y = (hv[2 * g].y + hv[2 * g + 1].y) * 0.5f;
  }
#pragma unroll
  for (int g = 0; g < 4; ++g) {
    p3[g].x = (hv[3 * g].x + hv[3 * g + 1].x + hv[3 * g + 2].x) * (1.f / 3.f);
    p3[g].y = (hv[3 * g].y + hv[3 * g + 1].y + hv[3 * g + 2].y) * (1.f / 3.f);
  }
#pragma unroll
  for (int g = 0; g < 3; ++g) {
    p4[g].x = (hv[4 * g].x + hv[4 * g + 1].x + hv[4 * g + 2].x + hv[4 * g + 3].x) * 0.25f;
    p4[g].y = (hv[4 * g].y + hv[4 * g + 1].y + hv[4 * g + 2].y + hv[4 * g + 3].y) * 0.25f;
  }

#pragma unroll
  for (int o = 0; o < 3; ++o) {
    const int orow = j12 * 3 + o;
    if (orow < 1024) {
      float ox = 0.f, oy = 0.f;
#pragma unroll
      for (int rr = 0; rr < 4; ++rr) {
        const int r = 4 * o + rr;
        const float4 wv = wgtS[r];
        const float2 p1 = hv[r];
        const float2 q2 = p2[r >> 1];
        const float2 q3 = p3[r / 3];
        const float2 q4 = p4[o];
        ox += wv.x * p1.x + wv.y * q2.x + wv.z * q3.x + wv.w * q4.x;
        oy += wv.x * p1.y + wv.y * q2.y + wv.z * q3.y + wv.w * q4.y;
      }
      float2 ov; ov.x = ox * 0.25f; ov.y = oy * 0.25f;
      *(float2*)(out + (size_t)(b * 1024 + orow) * D_ + d) = ov;
    }
  }
}

extern "C" void kernel_launch(void* const* d_in, const int* in_sizes, int n_in,
                              void* d_out, int out_size, void* d_ws, size_t ws_size,
                              hipStream_t stream) {
  const int*   x       = (const int*)d_in[0];
  const float* emb     = (const float*)d_in[1];
  const float* conv_w  = (const float*)d_in[2];
  const float* conv_b  = (const float*)d_in[3];
  const float* proj_w  = (const float*)d_in[4];
  const float* proj_b  = (const float*)d_in[5];
  const float* score_w = (const float*)d_in[6];
  const float* score_b = (const float*)d_in[7];
  float* out = (float*)d_out;

  char* ws = (char*)d_ws;
  size_t off = 0;
  float*    G      = (float*)(ws + off); off += (size_t)4 * 256 * 512 * 4;  // 2 MB
  float*    bias   = (float*)(ws + off); off += (size_t)512 * 4;
  float*    Zg     = (float*)(ws + off); off += (size_t)B_ * NF * 5 * 4;    // 16.8 KB
  unsigned* featPk = (unsigned*)(ws + off); off += (size_t)1024;
  float*    featCf = (float*)(ws + off); off += (size_t)1024;
  float*    TS     = (float*)(ws + off); off += (size_t)1024 * 4;           // 4 KB
  float*    c0     = (float*)(ws + off); off += (size_t)16;
  (void)in_sizes; (void)n_in; (void)out_size; (void)ws_size;

  k_g<<<101, 256, 0, stream>>>(emb, proj_w, conv_w, conv_b, proj_b, score_w,
                               G, bias, featPk, featCf, Zg, TS, c0);
  k_zphi<<<B_ * ZCHUNKS, 256, 0, stream>>>(x, TS, c0, score_b, featPk, Zg);
  k_fuse<<<B_ * 342, 256, 0, stream>>>(x, G, bias, TS, c0, score_b, featPk, featCf, Zg, out);
}

// Round 6
// 140.515 us; speedup vs baseline: 2.3365x; 1.0034x over previous
//
#include <hip/hip_runtime.h>
#include <hip/hip_bf16.h>

#define B_ 4
#define N_ 4096
#define L_ 4104
#define D_ 512
#define BK 64
#define NF 210     // monomials of degree <=6 in 4 vars
#define ZCH 36     // zphi chunk length (multiple of 12 -> aligned pooling windows)
#define ZCHUNKS 114  // 114*36 == 4104 == L_
#define PST 37     // P LDS row stride (coprime with 32 -> conflict-free column reads)

typedef __attribute__((ext_vector_type(8))) short bf16x8;
typedef __attribute__((ext_vector_type(4))) float f32x4;

__device__ __forceinline__ float bf2f(unsigned short u) {
  union { unsigned u; float f; } c; c.u = ((unsigned)u) << 16; return c.f;
}

// ---------------- K0: G_k = bf16(emb*cw_k) @ bf16(W)^T + bias' + feature table --------
__global__ __launch_bounds__(256) void k_g(const float* __restrict__ emb,
    const float* __restrict__ pw, const float* __restrict__ cwp,
    const float* __restrict__ cb, const float* __restrict__ pb,
    float* __restrict__ G, float* __restrict__ biasp,
    unsigned* __restrict__ featPk, float* __restrict__ featCf) {
  __shared__ __align__(16) __hip_bfloat16 As[2][64 * BK];
  __shared__ __align__(16) __hip_bfloat16 Bs[2][128 * BK];
  __shared__ __align__(16) float cwS[512];
  __shared__ float red[4];
  const int bx = blockIdx.x;
  const int t = threadIdx.x;
  const int w = t >> 6, l = t & 63;

  if (bx == 128) {                       // build Taylor feature table (uniform loop, no divergence)
    if (t < NF) {
      int idx = 0, mp = 0, mq = 0, mr = 0, ms = 0;
      for (int m = 0; m <= 6; ++m)
        for (int p = m; p >= 0; --p)
          for (int q = m - p; q >= 0; --q)
            for (int r = m - p - q; r >= 0; --r) {
              const int s4 = m - p - q - r;
              if (idx == t) { mp = p; mq = q; mr = r; ms = s4; }
              ++idx;
            }
      featPk[t] = (unsigned)mp | ((unsigned)mq << 8) | ((unsigned)mr << 16) | ((unsigned)ms << 24);
      const float invf[7] = {1.f, 1.f, 0.5f, 1.f/6.f, 1.f/24.f, 1.f/120.f, 1.f/720.f};
      featCf[t] = invf[mp] * invf[mq] * invf[mr] * invf[ms];
    }
    return;
  }
  if (bx >= 64) {                        // bias'[o] = cb . W[o,:] + pb[o], coalesced by column
    const int o0 = (bx - 64) * 8;
    const float2 cv = *(const float2*)(cb + t * 2);
#pragma unroll
    for (int oo = 0; oo < 8; ++oo) {
      const int o = o0 + oo;
      const float2 wv = *(const float2*)(pw + (size_t)o * 512 + t * 2);
      float s = wv.x * cv.x + wv.y * cv.y;
#pragma unroll
      for (int off = 32; off > 0; off >>= 1) s += __shfl_xor(s, off);
      if (l == 0) red[w] = s;
      __syncthreads();
      if (t == 0) biasp[o] = red[0] + red[1] + red[2] + red[3] + pb[o];
      __syncthreads();
    }
    return;
  }

  const int m0 = (bx & 3) * 64;          // token tile
  const int n0 = ((bx >> 2) & 3) * 128;  // output-channel tile
  const int kp = bx >> 4;                // conv tap 0..3
  const int quad = l >> 4, r16 = l & 15;
  const int wc = w * 32;

  cwS[t]       = cwp[t * 4 + kp];
  cwS[t + 256] = cwp[(t + 256) * 4 + kp];

  f32x4 acc[4][2];
#pragma unroll
  for (int a = 0; a < 4; ++a)
#pragma unroll
    for (int bq = 0; bq < 2; ++bq) acc[a][bq] = (f32x4){0.f, 0.f, 0.f, 0.f};

  const int ra = t >> 2, ga0 = (t & 3) * 2;
  const int rb = t >> 1, gb0 = (t & 1) * 4;

#define STAGEG(buf, kb)                                                          \
  _Pragma("unroll")                                                              \
  for (int gi = 0; gi < 2; ++gi) {                                               \
    const int g = ga0 + gi;                                                      \
    const int c0 = (kb) + g * 8;                                                 \
    const float4 a0 = *(const float4*)(emb + (size_t)(m0 + ra) * 512 + c0);      \
    const float4 a1 = *(const float4*)(emb + (size_t)(m0 + ra) * 512 + c0 + 4);  \
    const float4 w0 = *(const float4*)(cwS + c0);                                \
    const float4 w1 = *(const float4*)(cwS + c0 + 4);                            \
    union { __hip_bfloat16 q[8]; bf16x8 v; } ua;                                 \
    ua.q[0] = __float2bfloat16(a0.x * w0.x); ua.q[1] = __float2bfloat16(a0.y * w0.y); \
    ua.q[2] = __float2bfloat16(a0.z * w0.z); ua.q[3] = __float2bfloat16(a0.w * w0.w); \
    ua.q[4] = __float2bfloat16(a1.x * w1.x); ua.q[5] = __float2bfloat16(a1.y * w1.y); \
    ua.q[6] = __float2bfloat16(a1.z * w1.z); ua.q[7] = __float2bfloat16(a1.w * w1.w); \
    *(bf16x8*)(&As[buf][ra * BK + ((g ^ (ra & 7)) * 8)]) = ua.v;                 \
  }                                                                              \
  _Pragma("unroll")                                                              \
  for (int gi = 0; gi < 4; ++gi) {                                               \
    const int g = gb0 + gi;                                                      \
    const int c0 = (kb) + g * 8;                                                 \
    const float4 b0 = *(const float4*)(pw + (size_t)(n0 + rb) * 512 + c0);       \
    const float4 b1 = *(const float4*)(pw + (size_t)(n0 + rb) * 512 + c0 + 4);   \
    union { __hip_bfloat16 q[8]; bf16x8 v; } ub;                                 \
    ub.q[0] = __float2bfloat16(b0.x); ub.q[1] = __float2bfloat16(b0.y);          \
    ub.q[2] = __float2bfloat16(b0.z); ub.q[3] = __float2bfloat16(b0.w);          \
    ub.q[4] = __float2bfloat16(b1.x); ub.q[5] = __float2bfloat16(b1.y);          \
    ub.q[6] = __float2bfloat16(b1.z); ub.q[7] = __float2bfloat16(b1.w);          \
    *(bf16x8*)(&Bs[buf][rb * BK + ((g ^ (rb & 7)) * 8)]) = ub.v;                 \
  }

  __syncthreads();        // cwS ready
  STAGEG(0, 0)
  __syncthreads();

#pragma unroll 1
  for (int kt = 0; kt < 8; ++kt) {
    const int cur = kt & 1;
    if (kt < 7) { STAGEG(1 - cur, (kt + 1) * BK) }
#pragma unroll
    for (int kk = 0; kk < 2; ++kk) {
      const int col_e = (kk * 32 + quad * 8) ^ ((r16 & 7) * 8);
      bf16x8 af[4], bfr[2];
#pragma unroll
      for (int ti = 0; ti < 4; ++ti)
        af[ti] = *(const bf16x8*)(&As[cur][(ti * 16 + r16) * BK + col_e]);
#pragma unroll
      for (int tj = 0; tj < 2; ++tj)
        bfr[tj] = *(const bf16x8*)(&Bs[cur][(wc + tj * 16 + r16) * BK + col_e]);
#pragma unroll
      for (int ti = 0; ti < 4; ++ti)
#pragma unroll
        for (int tj = 0; tj < 2; ++tj)
          acc[ti][tj] = __builtin_amdgcn_mfma_f32_16x16x32_bf16(af[ti], bfr[tj], acc[ti][tj], 0, 0, 0);
    }
    __syncthreads();
  }
#undef STAGEG

#pragma unroll
  for (int ti = 0; ti < 4; ++ti) {
    const int gi0 = m0 + ti * 16 + quad * 4;
#pragma unroll
    for (int tj = 0; tj < 2; ++tj) {
      const int go = n0 + wc + tj * 16 + r16;
#pragma unroll
      for (int r = 0; r < 4; ++r)
        G[((size_t)kp * 256 + gi0 + r) * 512 + go] = acc[ti][tj][r];
    }
  }
}

// ---------------- K1: h[i] = sum_k G_k[x[i+k]] + bias' (bf16) + t = h.sw + zero Z ------
__global__ __launch_bounds__(256) void k_h(const int* __restrict__ x,
    const float* __restrict__ G, const float* __restrict__ biasp,
    const float* __restrict__ sw, unsigned* __restrict__ h,
    float* __restrict__ tb, float* __restrict__ Zg) {
  __shared__ int tokS[11];
  __shared__ float tpart[8][4];
  const int bx = blockIdx.x;             // 2048: b*512 + rowgroup
  const int b = bx >> 9, i0 = (bx & 511) * 8;
  const int t = threadIdx.x, d = t * 2, w = t >> 6, l = t & 63;
  if (bx < 17) {                         // zero the 4*NF*5 moment buffer
    const int zi = bx * 256 + t;
    if (zi < B_ * NF * 5) Zg[zi] = 0.f;
  }
  if (t < 11) {
    const int j = i0 + t;
    tokS[t] = (j < N_) ? x[b * N_ + j] : 0;
  }
  __syncthreads();
  const float2 bp  = *(const float2*)(biasp + d);
  const float2 swv = *(const float2*)(sw + d);
#pragma unroll
  for (int r = 0; r < 8; ++r) {
    const int i = i0 + r;
    float2 acc = bp;
#pragma unroll
    for (int k = 0; k < 4; ++k) {
      if (i + k < N_) {
        const float2 g = *(const float2*)(G + ((size_t)k * 256 + tokS[r + k]) * 512 + d);
        acc.x += g.x; acc.y += g.y;
      }
    }
    union { __hip_bfloat16 q[2]; unsigned u; } pk;
    pk.q[0] = __float2bfloat16(acc.x);
    pk.q[1] = __float2bfloat16(acc.y);
    h[(size_t)(b * N_ + i) * 256 + t] = pk.u;
    float v = acc.x * swv.x + acc.y * swv.y;
#pragma unroll
    for (int off = 32; off > 0; off >>= 1) v += __shfl_xor(v, off);
    if (l == 0) tpart[r][w] = v;
  }
  __syncthreads();
  if (t < 8)
    tb[b * N_ + i0 + t] = tpart[t][0] + tpart[t][1] + tpart[t][2] + tpart[t][3];
}

// helper: 4-way softmax from a t-window in LDS
__device__ __forceinline__ float4 softmax4(const float* __restrict__ tw, int base,
                                           int i, float bb) {
  const float s0 = tw[i - base] + bb;
  const int j2 = i & ~1;
  const float s1 = (tw[j2 - base] + tw[j2 + 1 - base]) * 0.5f + bb;
  const int j3 = (i / 3) * 3;
  const float s2 = (tw[j3 - base] + tw[j3 + 1 - base] + tw[j3 + 2 - base]) * (1.f / 3.f) + bb;
  const int j4 = i & ~3;
  const float s3 = (tw[j4 - base] + tw[j4 + 1 - base] + tw[j4 + 2 - base] + tw[j4 + 3 - base]) * 0.25f + bb;
  const float m = fmaxf(fmaxf(s0, s1), fmaxf(s2, s3));
  const float e0 = __expf(s0 - m), e1 = __expf(s1 - m), e2 = __expf(s2 - m), e3 = __expf(s3 - m);
  const float inv = 1.f / (e0 + e1 + e2 + e3);
  return make_float4(e0 * inv, e1 * inv, e2 * inv, e3 * inv);
}

// ---------------- K2: j-side moments  Z[alpha] = sum_j s_j^alpha * [s_j;1]
// 456 blocks of 36 positions; t-window from tb; P transposed -> conflict-free
__global__ __launch_bounds__(256) void k_zphi(const float* __restrict__ tb,
    const float* __restrict__ sb, const unsigned* __restrict__ featPk,
    float* __restrict__ Zg) {
  __shared__ float twj[ZCH];
  __shared__ float P[32][PST];
  __shared__ unsigned pkS[NF];
  const int bx = blockIdx.x;             // B_*ZCHUNKS
  const int b = bx / ZCHUNKS, jc = bx % ZCHUNKS;
  const int t = threadIdx.x;
  const int j0 = jc * ZCH;               // multiple of 12 -> pooling windows stay in-tile
  if (t < NF) pkS[t] = featPk[t];
  if (t < ZCH) {
    const int j = j0 + t;
    twj[t] = (j < N_) ? tb[b * N_ + j] : 0.f;
  }
  __syncthreads();
  const float bb = sb[0];
  if (t < ZCH) {
    const float4 s = softmax4(twj, j0, j0 + t, bb);
    P[0][t] = 1.f; P[8][t] = 1.f; P[16][t] = 1.f; P[24][t] = 1.f;
    float va = 1.f, vb = 1.f, vc = 1.f, vd = 1.f;
#pragma unroll
    for (int e = 1; e < 8; ++e) {
      va *= s.x; vb *= s.y; vc *= s.z; vd *= s.w;
      P[e][t] = va; P[8 + e][t] = vb; P[16 + e][t] = vc; P[24 + e][t] = vd;
    }
  }
  __syncthreads();
  if (t < NF) {
    const unsigned pk = pkS[t];
    const int p = pk & 255, q = (pk >> 8) & 255, r = (pk >> 16) & 255, s4 = pk >> 24;
    const float* Ra0 = &P[p][0];       const float* Ra1 = &P[p + 1][0];
    const float* Rb0 = &P[8 + q][0];   const float* Rb1 = &P[8 + q + 1][0];
    const float* Rc0 = &P[16 + r][0];  const float* Rc1 = &P[16 + r + 1][0];
    const float* Rd0 = &P[24 + s4][0]; const float* Rd1 = &P[24 + s4 + 1][0];
    float z0 = 0.f, z1 = 0.f, z2 = 0.f, z3 = 0.f, z4 = 0.f;
#pragma unroll 4
    for (int jj = 0; jj < ZCH; ++jj) {
      const float pa0 = Ra0[jj], pa1 = Ra1[jj];
      const float pb0 = Rb0[jj], pb1 = Rb1[jj];
      const float pc0 = Rc0[jj], pc1 = Rc1[jj];
      const float pd0 = Rd0[jj], pd1 = Rd1[jj];
      const float cd = pc0 * pd0, ab = pa0 * pb0;
      z4 += pa0 * (pb0 * cd);
      z0 += pa1 * (pb0 * cd);
      z1 += pb1 * (pa0 * cd);
      z2 += pc1 * (ab * pd0);
      z3 += pd1 * (ab * pc0);
    }
    float* zb = Zg + (size_t)(b * NF + t) * 5;
    atomicAdd(zb + 0, z0); atomicAdd(zb + 1, z1); atomicAdd(zb + 2, z2);
    atomicAdd(zb + 3, z3); atomicAdd(zb + 4, z4);
  }
}

// ---------------- K3: 12-row tiles: wgt from phi(s_i).Z, pool h once, downsample -------
__global__ __launch_bounds__(256) void k_fuse(const __hip_bfloat16* __restrict__ h,
    const float* __restrict__ tb, const float* __restrict__ sb,
    const unsigned* __restrict__ featPk, const float* __restrict__ featCf,
    const float* __restrict__ Zg, float* __restrict__ out) {
  __shared__ __align__(16) float4 wgtS[12];
  __shared__ float tbS[12];
  __shared__ float Pr[12][32];
  __shared__ float Zl[NF * 5];
  __shared__ unsigned pkS[NF];
  __shared__ float cfS[NF];
  const int bx = blockIdx.x;
  const int b = bx / 342, j12 = bx % 342;
  const int t = threadIdx.x, d = t * 2;
  const int r0 = 12 * j12;

  if (t < NF) { pkS[t] = featPk[t]; cfS[t] = featCf[t]; }
  for (int i2 = t; i2 < NF * 5; i2 += 256) Zl[i2] = Zg[(size_t)b * NF * 5 + i2];
  if (t < 12) {
    const int row = r0 + t;
    tbS[t] = (row < N_) ? tb[b * N_ + row] : 0.f;
  }
  __syncthreads();
  if (t < 12) {                          // powers of s_i for this tile's 12 rows
    const float4 s = softmax4(tbS, r0, r0 + t, sb[0]);
    float* p = &Pr[t][0];
    float va = 1.f, vb = 1.f, vc = 1.f, vd = 1.f;
    p[0] = 1.f; p[8] = 1.f; p[16] = 1.f; p[24] = 1.f;
#pragma unroll
    for (int e = 1; e < 8; ++e) {
      va *= s.x; vb *= s.y; vc *= s.z; vd *= s.w;
      p[e] = va; p[8 + e] = vb; p[16 + e] = vc; p[24 + e] = vd;
    }
  }
  __syncthreads();
  if (t < 192) {                         // 16 lanes per row evaluate phi . Z
    const int row = t >> 4, fi = t & 15;
    float n0 = 0.f, n1 = 0.f, n2 = 0.f, n3 = 0.f, dn = 0.f;
    const float* pr = &Pr[row][0];
    for (int f = fi; f < NF; f += 16) {
      const unsigned pk = pkS[f];
      const float val = cfS[f] * pr[pk & 255] * pr[8 + ((pk >> 8) & 255)]
                                * pr[16 + ((pk >> 16) & 255)] * pr[24 + (pk >> 24)];
      const float* z = &Zl[f * 5];
      n0 += val * z[0]; n1 += val * z[1]; n2 += val * z[2]; n3 += val * z[3];
      dn += val * z[4];
    }
#pragma unroll
    for (int m = 8; m >= 1; m >>= 1) {
      n0 += __shfl_xor(n0, m); n1 += __shfl_xor(n1, m); n2 += __shfl_xor(n2, m);
      n3 += __shfl_xor(n3, m); dn += __shfl_xor(dn, m);
    }
    if (fi == 0) {
      const float inv = 1.f / dn;
      wgtS[row] = make_float4(n0 * inv, n1 * inv, n2 * inv, n3 * inv);
    }
  }
  __syncthreads();

  const __hip_bfloat16* hb = h + (size_t)b * N_ * D_;
  float2 hv[12];
#pragma unroll
  for (int q = 0; q < 12; ++q) {
    const int row = r0 + q;
    if (row < N_) {
      const ushort2 u = *(const ushort2*)(hb + (size_t)row * D_ + d);
      hv[q] = make_float2(bf2f(u.x), bf2f(u.y));
    } else {
      hv[q] = make_float2(0.f, 0.f);
    }
  }

  float2 p2[6], p3[4], p4[3];
#pragma unroll
  for (int g = 0; g < 6; ++g) {
    p2[g].x = (hv[2 * g].x + hv[2 * g + 1].x) * 0.5f;
    p2[g].y = (hv[2 * g].y + hv[2 * g + 1].y) * 0.5f;
  }
#pragma unroll
  for (int g = 0; g < 4; ++g) {
    p3[g].x = (hv[3 * g].x + hv[3 * g + 1].x + hv[3 * g + 2].x) * (1.f / 3.f);
    p3[g].y = (hv[3 * g].y + hv[3 * g + 1].y + hv[3 * g + 2].y) * (1.f / 3.f);
  }
#pragma unroll
  for (int g = 0; g < 3; ++g) {
    p4[g].x = (hv[4 * g].x + hv[4 * g + 1].x + hv[4 * g + 2].x + hv[4 * g + 3].x) * 0.25f;
    p4[g].y = (hv[4 * g].y + hv[4 * g + 1].y + hv[4 * g + 2].y + hv[4 * g + 3].y) * 0.25f;
  }

#pragma unroll
  for (int o = 0; o < 3; ++o) {
    const int orow = j12 * 3 + o;
    if (orow < 1024) {
      float ox = 0.f, oy = 0.f;
#pragma unroll
      for (int rr = 0; rr < 4; ++rr) {
        const int r = 4 * o + rr;
        const float4 wv = wgtS[r];
        const float2 p1 = hv[r];
        const float2 q2 = p2[r >> 1];
        const float2 q3 = p3[r / 3];
        const float2 q4 = p4[o];
        ox += wv.x * p1.x + wv.y * q2.x + wv.z * q3.x + wv.w * q4.x;
        oy += wv.x * p1.y + wv.y * q2.y + wv.z * q3.y + wv.w * q4.y;
      }
      float2 ov; ov.x = ox * 0.25f; ov.y = oy * 0.25f;
      *(float2*)(out + (size_t)(b * 1024 + orow) * D_ + d) = ov;
    }
  }
}

extern "C" void kernel_launch(void* const* d_in, const int* in_sizes, int n_in,
                              void* d_out, int out_size, void* d_ws, size_t ws_size,
                              hipStream_t stream) {
  const int*   x       = (const int*)d_in[0];
  const float* emb     = (const float*)d_in[1];
  const float* conv_w  = (const float*)d_in[2];
  const float* conv_b  = (const float*)d_in[3];
  const float* proj_w  = (const float*)d_in[4];
  const float* proj_b  = (const float*)d_in[5];
  const float* score_w = (const float*)d_in[6];
  const float* score_b = (const float*)d_in[7];
  float* out = (float*)d_out;

  char* ws = (char*)d_ws;
  size_t off = 0;
  float*          G    = (float*)(ws + off);          off += (size_t)4 * 256 * 512 * 4;  // 2 MB
  float*          bias = (float*)(ws + off);          off += (size_t)512 * 4;
  __hip_bfloat16* h    = (__hip_bfloat16*)(ws + off); off += (size_t)16384 * 512 * 2;    // 16 MB
  float*          tb   = (float*)(ws + off);          off += (size_t)16384 * 4;
  float*          Zg   = (float*)(ws + off);          off += (size_t)B_ * NF * 5 * 4;
  unsigned*       featPk = (unsigned*)(ws + off);     off += (size_t)NF * 4;
  float*          featCf = (float*)(ws + off);        off += (size_t)NF * 4;
  (void)in_sizes; (void)n_in; (void)out_size; (void)ws_size;

  k_g<<<129, 256, 0, stream>>>(emb, proj_w, conv_w, conv_b, proj_b, G, bias, featPk, featCf);
  k_h<<<2048, 256, 0, stream>>>(x, G, bias, score_w, (unsigned*)h, tb, Zg);
  k_zphi<<<B_ * ZCHUNKS, 256, 0, stream>>>(tb, score_b, featPk, Zg);
  k_fuse<<<B_ * 342, 256, 0, stream>>>(h, tb, score_b, featPk, featCf, Zg, out);
}

// Round 7
// 136.201 us; speedup vs baseline: 2.4105x; 1.0317x over previous
//
#include <hip/hip_runtime.h>
#include <hip/hip_bf16.h>

#define B_ 4
#define N_ 4096
#define L_ 4104
#define D_ 512
#define BK 64
#define NF 210     // monomials of degree <=6 in 4 vars
#define ZCH 36     // zphi chunk length (multiple of 12 -> aligned pooling windows)
#define ZGRP 19    // partial-Z groups per batch (no atomics; k_fuse sums partials)
#define ZCHPB 6    // chunks per zphi block: 19*6 = 114 chunks = L_/ZCH
#define PST 37     // P LDS row stride (coprime with 32 -> conflict-free column reads)

typedef __attribute__((ext_vector_type(8))) short bf16x8;
typedef __attribute__((ext_vector_type(4))) float f32x4;

__device__ __forceinline__ float bf2f(unsigned short u) {
  union { unsigned u; float f; } c; c.u = ((unsigned)u) << 16; return c.f;
}

// ---------------- K0: G_k = bf16(emb*cw_k) @ bf16(W)^T + bias' + feature table --------
__global__ __launch_bounds__(256) void k_g(const float* __restrict__ emb,
    const float* __restrict__ pw, const float* __restrict__ cwp,
    const float* __restrict__ cb, const float* __restrict__ pb,
    float* __restrict__ G, float* __restrict__ biasp,
    unsigned* __restrict__ featPk, float* __restrict__ featCf) {
  __shared__ __align__(16) __hip_bfloat16 As[2][64 * BK];
  __shared__ __align__(16) __hip_bfloat16 Bs[2][128 * BK];
  __shared__ __align__(16) float cwS[512];
  __shared__ float red[4];
  const int bx = blockIdx.x;
  const int t = threadIdx.x;
  const int w = t >> 6, l = t & 63;

  if (bx == 128) {                       // build Taylor feature table (uniform loop, no divergence)
    if (t < NF) {
      int idx = 0, mp = 0, mq = 0, mr = 0, ms = 0;
      for (int m = 0; m <= 6; ++m)
        for (int p = m; p >= 0; --p)
          for (int q = m - p; q >= 0; --q)
            for (int r = m - p - q; r >= 0; --r) {
              const int s4 = m - p - q - r;
              if (idx == t) { mp = p; mq = q; mr = r; ms = s4; }
              ++idx;
            }
      featPk[t] = (unsigned)mp | ((unsigned)mq << 8) | ((unsigned)mr << 16) | ((unsigned)ms << 24);
      const float invf[7] = {1.f, 1.f, 0.5f, 1.f/6.f, 1.f/24.f, 1.f/120.f, 1.f/720.f};
      featCf[t] = invf[mp] * invf[mq] * invf[mr] * invf[ms];
    }
    return;
  }
  if (bx >= 64) {                        // bias'[o] = cb . W[o,:] + pb[o], coalesced by column
    const int o0 = (bx - 64) * 8;
    const float2 cv = *(const float2*)(cb + t * 2);
#pragma unroll
    for (int oo = 0; oo < 8; ++oo) {
      const int o = o0 + oo;
      const float2 wv = *(const float2*)(pw + (size_t)o * 512 + t * 2);
      float s = wv.x * cv.x + wv.y * cv.y;
#pragma unroll
      for (int off = 32; off > 0; off >>= 1) s += __shfl_xor(s, off);
      if (l == 0) red[w] = s;
      __syncthreads();
      if (t == 0) biasp[o] = red[0] + red[1] + red[2] + red[3] + pb[o];
      __syncthreads();
    }
    return;
  }

  const int m0 = (bx & 3) * 64;          // token tile
  const int n0 = ((bx >> 2) & 3) * 128;  // output-channel tile
  const int kp = bx >> 4;                // conv tap 0..3
  const int quad = l >> 4, r16 = l & 15;
  const int wc = w * 32;

  cwS[t]       = cwp[t * 4 + kp];
  cwS[t + 256] = cwp[(t + 256) * 4 + kp];

  f32x4 acc[4][2];
#pragma unroll
  for (int a = 0; a < 4; ++a)
#pragma unroll
    for (int bq = 0; bq < 2; ++bq) acc[a][bq] = (f32x4){0.f, 0.f, 0.f, 0.f};

  const int ra = t >> 2, ga0 = (t & 3) * 2;
  const int rb = t >> 1, gb0 = (t & 1) * 4;

#define STAGEG(buf, kb)                                                          \
  _Pragma("unroll")                                                              \
  for (int gi = 0; gi < 2; ++gi) {                                               \
    const int g = ga0 + gi;                                                      \
    const int c0 = (kb) + g * 8;                                                 \
    const float4 a0 = *(const float4*)(emb + (size_t)(m0 + ra) * 512 + c0);      \
    const float4 a1 = *(const float4*)(emb + (size_t)(m0 + ra) * 512 + c0 + 4);  \
    const float4 w0 = *(const float4*)(cwS + c0);                                \
    const float4 w1 = *(const float4*)(cwS + c0 + 4);                            \
    union { __hip_bfloat16 q[8]; bf16x8 v; } ua;                                 \
    ua.q[0] = __float2bfloat16(a0.x * w0.x); ua.q[1] = __float2bfloat16(a0.y * w0.y); \
    ua.q[2] = __float2bfloat16(a0.z * w0.z); ua.q[3] = __float2bfloat16(a0.w * w0.w); \
    ua.q[4] = __float2bfloat16(a1.x * w1.x); ua.q[5] = __float2bfloat16(a1.y * w1.y); \
    ua.q[6] = __float2bfloat16(a1.z * w1.z); ua.q[7] = __float2bfloat16(a1.w * w1.w); \
    *(bf16x8*)(&As[buf][ra * BK + ((g ^ (ra & 7)) * 8)]) = ua.v;                 \
  }                                                                              \
  _Pragma("unroll")                                                              \
  for (int gi = 0; gi < 4; ++gi) {                                               \
    const int g = gb0 + gi;                                                      \
    const int c0 = (kb) + g * 8;                                                 \
    const float4 b0 = *(const float4*)(pw + (size_t)(n0 + rb) * 512 + c0);       \
    const float4 b1 = *(const float4*)(pw + (size_t)(n0 + rb) * 512 + c0 + 4);   \
    union { __hip_bfloat16 q[8]; bf16x8 v; } ub;                                 \
    ub.q[0] = __float2bfloat16(b0.x); ub.q[1] = __float2bfloat16(b0.y);          \
    ub.q[2] = __float2bfloat16(b0.z); ub.q[3] = __float2bfloat16(b0.w);          \
    ub.q[4] = __float2bfloat16(b1.x); ub.q[5] = __float2bfloat16(b1.y);          \
    ub.q[6] = __float2bfloat16(b1.z); ub.q[7] = __float2bfloat16(b1.w);          \
    *(bf16x8*)(&Bs[buf][rb * BK + ((g ^ (rb & 7)) * 8)]) = ub.v;                 \
  }

  __syncthreads();        // cwS ready
  STAGEG(0, 0)
  __syncthreads();

#pragma unroll 1
  for (int kt = 0; kt < 8; ++kt) {
    const int cur = kt & 1;
    if (kt < 7) { STAGEG(1 - cur, (kt + 1) * BK) }
#pragma unroll
    for (int kk = 0; kk < 2; ++kk) {
      const int col_e = (kk * 32 + quad * 8) ^ ((r16 & 7) * 8);
      bf16x8 af[4], bfr[2];
#pragma unroll
      for (int ti = 0; ti < 4; ++ti)
        af[ti] = *(const bf16x8*)(&As[cur][(ti * 16 + r16) * BK + col_e]);
#pragma unroll
      for (int tj = 0; tj < 2; ++tj)
        bfr[tj] = *(const bf16x8*)(&Bs[cur][(wc + tj * 16 + r16) * BK + col_e]);
#pragma unroll
      for (int ti = 0; ti < 4; ++ti)
#pragma unroll
        for (int tj = 0; tj < 2; ++tj)
          acc[ti][tj] = __builtin_amdgcn_mfma_f32_16x16x32_bf16(af[ti], bfr[tj], acc[ti][tj], 0, 0, 0);
    }
    __syncthreads();
  }
#undef STAGEG

#pragma unroll
  for (int ti = 0; ti < 4; ++ti) {
    const int gi0 = m0 + ti * 16 + quad * 4;
#pragma unroll
    for (int tj = 0; tj < 2; ++tj) {
      const int go = n0 + wc + tj * 16 + r16;
#pragma unroll
      for (int r = 0; r < 4; ++r)
        G[((size_t)kp * 256 + gi0 + r) * 512 + go] = acc[ti][tj][r];
    }
  }
}

// ---------------- K1: h[i] = sum_k G_k[x[i+k]] + bias' (bf16) + t = h.sw ---------------
__global__ __launch_bounds__(256) void k_h(const int* __restrict__ x,
    const float* __restrict__ G, const float* __restrict__ biasp,
    const float* __restrict__ sw, unsigned* __restrict__ h,
    float* __restrict__ tb) {
  __shared__ int tokS[11];
  __shared__ float tpart[8][4];
  const int bx = blockIdx.x;             // 2048: b*512 + rowgroup
  const int b = bx >> 9, i0 = (bx & 511) * 8;
  const int t = threadIdx.x, d = t * 2, w = t >> 6, l = t & 63;
  if (t < 11) {
    const int j = i0 + t;
    tokS[t] = (j < N_) ? x[b * N_ + j] : 0;
  }
  __syncthreads();
  const float2 bp  = *(const float2*)(biasp + d);
  const float2 swv = *(const float2*)(sw + d);
#pragma unroll
  for (int r = 0; r < 8; ++r) {
    const int i = i0 + r;
    float2 acc = bp;
#pragma unroll
    for (int k = 0; k < 4; ++k) {
      if (i + k < N_) {
        const float2 g = *(const float2*)(G + ((size_t)k * 256 + tokS[r + k]) * 512 + d);
        acc.x += g.x; acc.y += g.y;
      }
    }
    union { __hip_bfloat16 q[2]; unsigned u; } pk;
    pk.q[0] = __float2bfloat16(acc.x);
    pk.q[1] = __float2bfloat16(acc.y);
    h[(size_t)(b * N_ + i) * 256 + t] = pk.u;
    float v = acc.x * swv.x + acc.y * swv.y;
#pragma unroll
    for (int off = 32; off > 0; off >>= 1) v += __shfl_xor(v, off);
    if (l == 0) tpart[r][w] = v;
  }
  __syncthreads();
  if (t < 8)
    tb[b * N_ + i0 + t] = tpart[t][0] + tpart[t][1] + tpart[t][2] + tpart[t][3];
}

// helper: 4-way softmax from a t-window in LDS
__device__ __forceinline__ float4 softmax4(const float* __restrict__ tw, int base,
                                           int i, float bb) {
  const float s0 = tw[i - base] + bb;
  const int j2 = i & ~1;
  const float s1 = (tw[j2 - base] + tw[j2 + 1 - base]) * 0.5f + bb;
  const int j3 = (i / 3) * 3;
  const float s2 = (tw[j3 - base] + tw[j3 + 1 - base] + tw[j3 + 2 - base]) * (1.f / 3.f) + bb;
  const int j4 = i & ~3;
  const float s3 = (tw[j4 - base] + tw[j4 + 1 - base] + tw[j4 + 2 - base] + tw[j4 + 3 - base]) * 0.25f + bb;
  const float m = fmaxf(fmaxf(s0, s1), fmaxf(s2, s3));
  const float e0 = __expf(s0 - m), e1 = __expf(s1 - m), e2 = __expf(s2 - m), e3 = __expf(s3 - m);
  const float inv = 1.f / (e0 + e1 + e2 + e3);
  return make_float4(e0 * inv, e1 * inv, e2 * inv, e3 * inv);
}

// ---------------- K2: j-side moments, ZERO atomics: per-group partials to Zp ----------
// grid B_*ZGRP; each block owns 6 chunks of 36, accumulates z in registers,
// plain-stores its partial; conflict-free transposed P[32][PST].
__global__ __launch_bounds__(256) void k_zphi(const float* __restrict__ tb,
    const float* __restrict__ sb, const unsigned* __restrict__ featPk,
    float* __restrict__ Zp) {
  __shared__ float twj[ZCH];
  __shared__ float P[32][PST];
  __shared__ unsigned pkS[NF];
  const int bx = blockIdx.x;             // B_*ZGRP
  const int b = bx / ZGRP, g = bx % ZGRP;
  const int t = threadIdx.x;
  if (t < NF) pkS[t] = featPk[t];
  const float bb = sb[0];
  float z0 = 0.f, z1 = 0.f, z2 = 0.f, z3 = 0.f, z4 = 0.f;
#pragma unroll 1
  for (int cc = 0; cc < ZCHPB; ++cc) {
    const int j0 = (g * ZCHPB + cc) * ZCH;
    __syncthreads();                     // prev chunk consumed (and pkS ready at cc=0)
    if (t < ZCH) {
      const int j = j0 + t;
      twj[t] = (j < N_) ? tb[b * N_ + j] : 0.f;
    }
    __syncthreads();
    if (t < ZCH) {
      const float4 s = softmax4(twj, j0, j0 + t, bb);
      P[0][t] = 1.f; P[8][t] = 1.f; P[16][t] = 1.f; P[24][t] = 1.f;
      float va = 1.f, vb = 1.f, vc = 1.f, vd = 1.f;
#pragma unroll
      for (int e = 1; e < 8; ++e) {
        va *= s.x; vb *= s.y; vc *= s.z; vd *= s.w;
        P[e][t] = va; P[8 + e][t] = vb; P[16 + e][t] = vc; P[24 + e][t] = vd;
      }
    }
    __syncthreads();
    if (t < NF) {
      const unsigned pk = pkS[t];
      const int p = pk & 255, q = (pk >> 8) & 255, r = (pk >> 16) & 255, s4 = pk >> 24;
      const float* Ra0 = &P[p][0];       const float* Ra1 = &P[p + 1][0];
      const float* Rb0 = &P[8 + q][0];   const float* Rb1 = &P[8 + q + 1][0];
      const float* Rc0 = &P[16 + r][0];  const float* Rc1 = &P[16 + r + 1][0];
      const float* Rd0 = &P[24 + s4][0]; const float* Rd1 = &P[24 + s4 + 1][0];
#pragma unroll 4
      for (int jj = 0; jj < ZCH; ++jj) {
        const float pa0 = Ra0[jj], pa1 = Ra1[jj];
        const float pb0 = Rb0[jj], pb1 = Rb1[jj];
        const float pc0 = Rc0[jj], pc1 = Rc1[jj];
        const float pd0 = Rd0[jj], pd1 = Rd1[jj];
        const float cd = pc0 * pd0, ab = pa0 * pb0;
        z4 += pa0 * (pb0 * cd);
        z0 += pa1 * (pb0 * cd);
        z1 += pb1 * (pa0 * cd);
        z2 += pc1 * (ab * pd0);
        z3 += pd1 * (ab * pc0);
      }
    }
  }
  if (t < NF) {
    float* zb = Zp + ((size_t)(b * ZGRP + g) * NF + t) * 5;
    zb[0] = z0; zb[1] = z1; zb[2] = z2; zb[3] = z3; zb[4] = z4;
  }
}

// ---------------- K3: 12-row tiles: wgt from phi(s_i).Z, pool h once, downsample -------
__global__ __launch_bounds__(256) void k_fuse(const __hip_bfloat16* __restrict__ h,
    const float* __restrict__ tb, const float* __restrict__ sb,
    const unsigned* __restrict__ featPk, const float* __restrict__ featCf,
    const float* __restrict__ Zp, float* __restrict__ out) {
  __shared__ __align__(16) float4 wgtS[12];
  __shared__ float tbS[12];
  __shared__ float Pr[12][32];
  __shared__ float Zl[NF * 5];
  __shared__ unsigned pkS[NF];
  __shared__ float cfS[NF];
  const int bx = blockIdx.x;
  const int b = bx / 342, j12 = bx % 342;
  const int t = threadIdx.x, d = t * 2;
  const int r0 = 12 * j12;

  if (t < NF) { pkS[t] = featPk[t]; cfS[t] = featCf[t]; }
  for (int i2 = t; i2 < NF * 5; i2 += 256) {   // sum the 19 partial Z's (L2-resident)
    const float* zp = Zp + (size_t)b * ZGRP * NF * 5 + i2;
    float a = 0.f;
#pragma unroll
    for (int gg = 0; gg < ZGRP; ++gg) a += zp[(size_t)gg * NF * 5];
    Zl[i2] = a;
  }
  if (t < 12) {
    const int row = r0 + t;
    tbS[t] = (row < N_) ? tb[b * N_ + row] : 0.f;
  }
  __syncthreads();
  if (t < 12) {                          // powers of s_i for this tile's 12 rows
    const float4 s = softmax4(tbS, r0, r0 + t, sb[0]);
    float* p = &Pr[t][0];
    float va = 1.f, vb = 1.f, vc = 1.f, vd = 1.f;
    p[0] = 1.f; p[8] = 1.f; p[16] = 1.f; p[24] = 1.f;
#pragma unroll
    for (int e = 1; e < 8; ++e) {
      va *= s.x; vb *= s.y; vc *= s.z; vd *= s.w;
      p[e] = va; p[8 + e] = vb; p[16 + e] = vc; p[24 + e] = vd;
    }
  }
  __syncthreads();
  if (t < 192) {                         // 16 lanes per row evaluate phi . Z
    const int row = t >> 4, fi = t & 15;
    float n0 = 0.f, n1 = 0.f, n2 = 0.f, n3 = 0.f, dn = 0.f;
    const float* pr = &Pr[row][0];
    for (int f = fi; f < NF; f += 16) {
      const unsigned pk = pkS[f];
      const float val = cfS[f] * pr[pk & 255] * pr[8 + ((pk >> 8) & 255)]
                                * pr[16 + ((pk >> 16) & 255)] * pr[24 + (pk >> 24)];
      const float* z = &Zl[f * 5];
      n0 += val * z[0]; n1 += val * z[1]; n2 += val * z[2]; n3 += val * z[3];
      dn += val * z[4];
    }
#pragma unroll
    for (int m = 8; m >= 1; m >>= 1) {
      n0 += __shfl_xor(n0, m); n1 += __shfl_xor(n1, m); n2 += __shfl_xor(n2, m);
      n3 += __shfl_xor(n3, m); dn += __shfl_xor(dn, m);
    }
    if (fi == 0) {
      const float inv = 1.f / dn;
      wgtS[row] = make_float4(n0 * inv, n1 * inv, n2 * inv, n3 * inv);
    }
  }
  __syncthreads();

  const __hip_bfloat16* hb = h + (size_t)b * N_ * D_;
  float2 hv[12];
#pragma unroll
  for (int q = 0; q < 12; ++q) {
    const int row = r0 + q;
    if (row < N_) {
      const ushort2 u = *(const ushort2*)(hb + (size_t)row * D_ + d);
      hv[q] = make_float2(bf2f(u.x), bf2f(u.y));
    } else {
      hv[q] = make_float2(0.f, 0.f);
    }
  }

  float2 p2[6], p3[4], p4[3];
#pragma unroll
  for (int g = 0; g < 6; ++g) {
    p2[g].x = (hv[2 * g].x + hv[2 * g + 1].x) * 0.5f;
    p2[g].y = (hv[2 * g].y + hv[2 * g + 1].y) * 0.5f;
  }
#pragma unroll
  for (int g = 0; g < 4; ++g) {
    p3[g].x = (hv[3 * g].x + hv[3 * g + 1].x + hv[3 * g + 2].x) * (1.f / 3.f);
    p3[g].y = (hv[3 * g].y + hv[3 * g + 1].y + hv[3 * g + 2].y) * (1.f / 3.f);
  }
#pragma unroll
  for (int g = 0; g < 3; ++g) {
    p4[g].x = (hv[4 * g].x + hv[4 * g + 1].x + hv[4 * g + 2].x + hv[4 * g + 3].x) * 0.25f;
    p4[g].y = (hv[4 * g].y + hv[4 * g + 1].y + hv[4 * g + 2].y + hv[4 * g + 3].y) * 0.25f;
  }

#pragma unroll
  for (int o = 0; o < 3; ++o) {
    const int orow = j12 * 3 + o;
    if (orow < 1024) {
      float ox = 0.f, oy = 0.f;
#pragma unroll
      for (int rr = 0; rr < 4; ++rr) {
        const int r = 4 * o + rr;
        const float4 wv = wgtS[r];
        const float2 p1 = hv[r];
        const float2 q2 = p2[r >> 1];
        const float2 q3 = p3[r / 3];
        const float2 q4 = p4[o];
        ox += wv.x * p1.x + wv.y * q2.x + wv.z * q3.x + wv.w * q4.x;
        oy += wv.x * p1.y + wv.y * q2.y + wv.z * q3.y + wv.w * q4.y;
      }
      float2 ov; ov.x = ox * 0.25f; ov.y = oy * 0.25f;
      *(float2*)(out + (size_t)(b * 1024 + orow) * D_ + d) = ov;
    }
  }
}

extern "C" void kernel_launch(void* const* d_in, const int* in_sizes, int n_in,
                              void* d_out, int out_size, void* d_ws, size_t ws_size,
                              hipStream_t stream) {
  const int*   x       = (const int*)d_in[0];
  const float* emb     = (const float*)d_in[1];
  const float* conv_w  = (const float*)d_in[2];
  const float* conv_b  = (const float*)d_in[3];
  const float* proj_w  = (const float*)d_in[4];
  const float* proj_b  = (const float*)d_in[5];
  const float* score_w = (const float*)d_in[6];
  const float* score_b = (const float*)d_in[7];
  float* out = (float*)d_out;

  char* ws = (char*)d_ws;
  size_t off = 0;
  float*          G    = (float*)(ws + off);          off += (size_t)4 * 256 * 512 * 4;  // 2 MB
  float*          bias = (float*)(ws + off);          off += (size_t)512 * 4;
  __hip_bfloat16* h    = (__hip_bfloat16*)(ws + off); off += (size_t)16384 * 512 * 2;    // 16 MB
  float*          tb   = (float*)(ws + off);          off += (size_t)16384 * 4;
  float*          Zp   = (float*)(ws + off);          off += (size_t)B_ * ZGRP * NF * 5 * 4; // 319 KB
  unsigned*       featPk = (unsigned*)(ws + off);     off += (size_t)NF * 4;
  float*          featCf = (float*)(ws + off);        off += (size_t)NF * 4;
  (void)in_sizes; (void)n_in; (void)out_size; (void)ws_size;

  k_g<<<129, 256, 0, stream>>>(emb, proj_w, conv_w, conv_b, proj_b, G, bias, featPk, featCf);
  k_h<<<2048, 256, 0, stream>>>(x, G, bias, score_w, (unsigned*)h, tb);
  k_zphi<<<B_ * ZGRP, 256, 0, stream>>>(tb, score_b, featPk, Zp);
  k_fuse<<<B_ * 342, 256, 0, stream>>>(h, tb, score_b, featPk, featCf, Zp, out);
}

// Round 8
// 132.361 us; speedup vs baseline: 2.4804x; 1.0290x over previous
//
#include <hip/hip_runtime.h>
#include <hip/hip_bf16.h>

#define B_ 4
#define N_ 4096
#define L_ 4104
#define D_ 512
#define BK 64
#define NF 210     // monomials of degree <=6 in 4 vars
#define ZCH 36     // zphi chunk length (multiple of 12 -> aligned pooling windows)
#define ZGRP 38    // partial-Z groups per batch (no atomics; k_fuse sums partials)
#define ZCHPB 3    // chunks per zphi block: 38*3 = 114 chunks = L_/ZCH
#define PST 37     // P LDS row stride (coprime with 32 -> conflict-free column reads)

typedef __attribute__((ext_vector_type(8))) short bf16x8;
typedef __attribute__((ext_vector_type(4))) float f32x4;

__device__ __forceinline__ float bf2f(unsigned short u) {
  union { unsigned u; float f; } c; c.u = ((unsigned)u) << 16; return c.f;
}

// ---------------- K0: G_k = bf16(emb*cw_k) @ bf16(W)^T + bias' + feature table --------
__global__ __launch_bounds__(256) void k_g(const float* __restrict__ emb,
    const float* __restrict__ pw, const float* __restrict__ cwp,
    const float* __restrict__ cb, const float* __restrict__ pb,
    float* __restrict__ G, float* __restrict__ biasp,
    unsigned* __restrict__ featPk, float* __restrict__ featCf) {
  __shared__ __align__(16) __hip_bfloat16 As[2][64 * BK];
  __shared__ __align__(16) __hip_bfloat16 Bs[2][128 * BK];
  __shared__ __align__(16) float cwS[512];
  __shared__ float red[4];
  const int bx = blockIdx.x;
  const int t = threadIdx.x;
  const int w = t >> 6, l = t & 63;

  if (bx == 128) {                       // build Taylor feature table (uniform loop, no divergence)
    if (t < NF) {
      int idx = 0, mp = 0, mq = 0, mr = 0, ms = 0;
      for (int m = 0; m <= 6; ++m)
        for (int p = m; p >= 0; --p)
          for (int q = m - p; q >= 0; --q)
            for (int r = m - p - q; r >= 0; --r) {
              const int s4 = m - p - q - r;
              if (idx == t) { mp = p; mq = q; mr = r; ms = s4; }
              ++idx;
            }
      featPk[t] = (unsigned)mp | ((unsigned)mq << 8) | ((unsigned)mr << 16) | ((unsigned)ms << 24);
      const float invf[7] = {1.f, 1.f, 0.5f, 1.f/6.f, 1.f/24.f, 1.f/120.f, 1.f/720.f};
      featCf[t] = invf[mp] * invf[mq] * invf[mr] * invf[ms];
    }
    return;
  }
  if (bx >= 64) {                        // bias'[o] = cb . W[o,:] + pb[o], coalesced by column
    const int o0 = (bx - 64) * 8;
    const float2 cv = *(const float2*)(cb + t * 2);
#pragma unroll
    for (int oo = 0; oo < 8; ++oo) {
      const int o = o0 + oo;
      const float2 wv = *(const float2*)(pw + (size_t)o * 512 + t * 2);
      float s = wv.x * cv.x + wv.y * cv.y;
#pragma unroll
      for (int off = 32; off > 0; off >>= 1) s += __shfl_xor(s, off);
      if (l == 0) red[w] = s;
      __syncthreads();
      if (t == 0) biasp[o] = red[0] + red[1] + red[2] + red[3] + pb[o];
      __syncthreads();
    }
    return;
  }

  const int m0 = (bx & 3) * 64;          // token tile
  const int n0 = ((bx >> 2) & 3) * 128;  // output-channel tile
  const int kp = bx >> 4;                // conv tap 0..3
  const int quad = l >> 4, r16 = l & 15;
  const int wc = w * 32;

  cwS[t]       = cwp[t * 4 + kp];
  cwS[t + 256] = cwp[(t + 256) * 4 + kp];

  f32x4 acc[4][2];
#pragma unroll
  for (int a = 0; a < 4; ++a)
#pragma unroll
    for (int bq = 0; bq < 2; ++bq) acc[a][bq] = (f32x4){0.f, 0.f, 0.f, 0.f};

  const int ra = t >> 2, ga0 = (t & 3) * 2;
  const int rb = t >> 1, gb0 = (t & 1) * 4;

#define STAGEG(buf, kb)                                                          \
  _Pragma("unroll")                                                              \
  for (int gi = 0; gi < 2; ++gi) {                                               \
    const int g = ga0 + gi;                                                      \
    const int c0 = (kb) + g * 8;                                                 \
    const float4 a0 = *(const float4*)(emb + (size_t)(m0 + ra) * 512 + c0);      \
    const float4 a1 = *(const float4*)(emb + (size_t)(m0 + ra) * 512 + c0 + 4);  \
    const float4 w0 = *(const float4*)(cwS + c0);                                \
    const float4 w1 = *(const float4*)(cwS + c0 + 4);                            \
    union { __hip_bfloat16 q[8]; bf16x8 v; } ua;                                 \
    ua.q[0] = __float2bfloat16(a0.x * w0.x); ua.q[1] = __float2bfloat16(a0.y * w0.y); \
    ua.q[2] = __float2bfloat16(a0.z * w0.z); ua.q[3] = __float2bfloat16(a0.w * w0.w); \
    ua.q[4] = __float2bfloat16(a1.x * w1.x); ua.q[5] = __float2bfloat16(a1.y * w1.y); \
    ua.q[6] = __float2bfloat16(a1.z * w1.z); ua.q[7] = __float2bfloat16(a1.w * w1.w); \
    *(bf16x8*)(&As[buf][ra * BK + ((g ^ (ra & 7)) * 8)]) = ua.v;                 \
  }                                                                              \
  _Pragma("unroll")                                                              \
  for (int gi = 0; gi < 4; ++gi) {                                               \
    const int g = gb0 + gi;                                                      \
    const int c0 = (kb) + g * 8;                                                 \
    const float4 b0 = *(const float4*)(pw + (size_t)(n0 + rb) * 512 + c0);       \
    const float4 b1 = *(const float4*)(pw + (size_t)(n0 + rb) * 512 + c0 + 4);   \
    union { __hip_bfloat16 q[8]; bf16x8 v; } ub;                                 \
    ub.q[0] = __float2bfloat16(b0.x); ub.q[1] = __float2bfloat16(b0.y);          \
    ub.q[2] = __float2bfloat16(b0.z); ub.q[3] = __float2bfloat16(b0.w);          \
    ub.q[4] = __float2bfloat16(b1.x); ub.q[5] = __float2bfloat16(b1.y);          \
    ub.q[6] = __float2bfloat16(b1.z); ub.q[7] = __float2bfloat16(b1.w);          \
    *(bf16x8*)(&Bs[buf][rb * BK + ((g ^ (rb & 7)) * 8)]) = ub.v;                 \
  }

  __syncthreads();        // cwS ready
  STAGEG(0, 0)
  __syncthreads();

#pragma unroll 1
  for (int kt = 0; kt < 8; ++kt) {
    const int cur = kt & 1;
    if (kt < 7) { STAGEG(1 - cur, (kt + 1) * BK) }
#pragma unroll
    for (int kk = 0; kk < 2; ++kk) {
      const int col_e = (kk * 32 + quad * 8) ^ ((r16 & 7) * 8);
      bf16x8 af[4], bfr[2];
#pragma unroll
      for (int ti = 0; ti < 4; ++ti)
        af[ti] = *(const bf16x8*)(&As[cur][(ti * 16 + r16) * BK + col_e]);
#pragma unroll
      for (int tj = 0; tj < 2; ++tj)
        bfr[tj] = *(const bf16x8*)(&Bs[cur][(wc + tj * 16 + r16) * BK + col_e]);
#pragma unroll
      for (int ti = 0; ti < 4; ++ti)
#pragma unroll
        for (int tj = 0; tj < 2; ++tj)
          acc[ti][tj] = __builtin_amdgcn_mfma_f32_16x16x32_bf16(af[ti], bfr[tj], acc[ti][tj], 0, 0, 0);
    }
    __syncthreads();
  }
#undef STAGEG

#pragma unroll
  for (int ti = 0; ti < 4; ++ti) {
    const int gi0 = m0 + ti * 16 + quad * 4;
#pragma unroll
    for (int tj = 0; tj < 2; ++tj) {
      const int go = n0 + wc + tj * 16 + r16;
#pragma unroll
      for (int r = 0; r < 4; ++r)
        G[((size_t)kp * 256 + gi0 + r) * 512 + go] = acc[ti][tj][r];
    }
  }
}

// ---------------- K1: h[i] = sum_k G_k[x[i+k]] + bias' (bf16) + t = h.sw ---------------
__global__ __launch_bounds__(256) void k_h(const int* __restrict__ x,
    const float* __restrict__ G, const float* __restrict__ biasp,
    const float* __restrict__ sw, unsigned* __restrict__ h,
    float* __restrict__ tb) {
  __shared__ int tokS[11];
  __shared__ float tpart[8][4];
  const int bx = blockIdx.x;             // 2048: b*512 + rowgroup
  const int b = bx >> 9, i0 = (bx & 511) * 8;
  const int t = threadIdx.x, d = t * 2, w = t >> 6, l = t & 63;
  if (t < 11) {
    const int j = i0 + t;
    tokS[t] = (j < N_) ? x[b * N_ + j] : 0;
  }
  __syncthreads();
  const float2 bp  = *(const float2*)(biasp + d);
  const float2 swv = *(const float2*)(sw + d);
#pragma unroll
  for (int r = 0; r < 8; ++r) {
    const int i = i0 + r;
    float2 acc = bp;
#pragma unroll
    for (int k = 0; k < 4; ++k) {
      if (i + k < N_) {
        const float2 g = *(const float2*)(G + ((size_t)k * 256 + tokS[r + k]) * 512 + d);
        acc.x += g.x; acc.y += g.y;
      }
    }
    union { __hip_bfloat16 q[2]; unsigned u; } pk;
    pk.q[0] = __float2bfloat16(acc.x);
    pk.q[1] = __float2bfloat16(acc.y);
    h[(size_t)(b * N_ + i) * 256 + t] = pk.u;
    float v = acc.x * swv.x + acc.y * swv.y;
#pragma unroll
    for (int off = 32; off > 0; off >>= 1) v += __shfl_xor(v, off);
    if (l == 0) tpart[r][w] = v;
  }
  __syncthreads();
  if (t < 8)
    tb[b * N_ + i0 + t] = tpart[t][0] + tpart[t][1] + tpart[t][2] + tpart[t][3];
}

// helper: 4-way softmax from a t-window in LDS
__device__ __forceinline__ float4 softmax4(const float* __restrict__ tw, int base,
                                           int i, float bb) {
  const float s0 = tw[i - base] + bb;
  const int j2 = i & ~1;
  const float s1 = (tw[j2 - base] + tw[j2 + 1 - base]) * 0.5f + bb;
  const int j3 = (i / 3) * 3;
  const float s2 = (tw[j3 - base] + tw[j3 + 1 - base] + tw[j3 + 2 - base]) * (1.f / 3.f) + bb;
  const int j4 = i & ~3;
  const float s3 = (tw[j4 - base] + tw[j4 + 1 - base] + tw[j4 + 2 - base] + tw[j4 + 3 - base]) * 0.25f + bb;
  const float m = fmaxf(fmaxf(s0, s1), fmaxf(s2, s3));
  const float e0 = __expf(s0 - m), e1 = __expf(s1 - m), e2 = __expf(s2 - m), e3 = __expf(s3 - m);
  const float inv = 1.f / (e0 + e1 + e2 + e3);
  return make_float4(e0 * inv, e1 * inv, e2 * inv, e3 * inv);
}

// ---------------- K2: j-side moments, ZERO atomics: per-group partials to Zp ----------
// grid B_*ZGRP; each block owns 3 chunks of 36, accumulates z in registers,
// plain-stores its partial; conflict-free transposed P[32][PST].
__global__ __launch_bounds__(256) void k_zphi(const float* __restrict__ tb,
    const float* __restrict__ sb, const unsigned* __restrict__ featPk,
    float* __restrict__ Zp) {
  __shared__ float twj[ZCH];
  __shared__ float P[32][PST];
  __shared__ unsigned pkS[NF];
  const int bx = blockIdx.x;             // B_*ZGRP
  const int b = bx / ZGRP, g = bx % ZGRP;
  const int t = threadIdx.x;
  if (t < NF) pkS[t] = featPk[t];
  const float bb = sb[0];
  float z0 = 0.f, z1 = 0.f, z2 = 0.f, z3 = 0.f, z4 = 0.f;
#pragma unroll 1
  for (int cc = 0; cc < ZCHPB; ++cc) {
    const int j0 = (g * ZCHPB + cc) * ZCH;
    __syncthreads();                     // prev chunk consumed (and pkS ready at cc=0)
    if (t < ZCH) {
      const int j = j0 + t;
      twj[t] = (j < N_) ? tb[b * N_ + j] : 0.f;
    }
    __syncthreads();
    if (t < ZCH) {
      const float4 s = softmax4(twj, j0, j0 + t, bb);
      P[0][t] = 1.f; P[8][t] = 1.f; P[16][t] = 1.f; P[24][t] = 1.f;
      float va = 1.f, vb = 1.f, vc = 1.f, vd = 1.f;
#pragma unroll
      for (int e = 1; e < 8; ++e) {
        va *= s.x; vb *= s.y; vc *= s.z; vd *= s.w;
        P[e][t] = va; P[8 + e][t] = vb; P[16 + e][t] = vc; P[24 + e][t] = vd;
      }
    }
    __syncthreads();
    if (t < NF) {
      const unsigned pk = pkS[t];
      const int p = pk & 255, q = (pk >> 8) & 255, r = (pk >> 16) & 255, s4 = pk >> 24;
      const float* Ra0 = &P[p][0];       const float* Ra1 = &P[p + 1][0];
      const float* Rb0 = &P[8 + q][0];   const float* Rb1 = &P[8 + q + 1][0];
      const float* Rc0 = &P[16 + r][0];  const float* Rc1 = &P[16 + r + 1][0];
      const float* Rd0 = &P[24 + s4][0]; const float* Rd1 = &P[24 + s4 + 1][0];
#pragma unroll 4
      for (int jj = 0; jj < ZCH; ++jj) {
        const float pa0 = Ra0[jj], pa1 = Ra1[jj];
        const float pb0 = Rb0[jj], pb1 = Rb1[jj];
        const float pc0 = Rc0[jj], pc1 = Rc1[jj];
        const float pd0 = Rd0[jj], pd1 = Rd1[jj];
        const float cd = pc0 * pd0, ab = pa0 * pb0;
        z4 += pa0 * (pb0 * cd);
        z0 += pa1 * (pb0 * cd);
        z1 += pb1 * (pa0 * cd);
        z2 += pc1 * (ab * pd0);
        z3 += pd1 * (ab * pc0);
      }
    }
  }
  if (t < NF) {
    float* zb = Zp + ((size_t)(b * ZGRP + g) * NF + t) * 5;
    zb[0] = z0; zb[1] = z1; zb[2] = z2; zb[3] = z3; zb[4] = z4;
  }
}

// ---------------- K3: 12-row tiles: wgt from phi(s_i).Z, pool h once, downsample -------
__global__ __launch_bounds__(256) void k_fuse(const __hip_bfloat16* __restrict__ h,
    const float* __restrict__ tb, const float* __restrict__ sb,
    const unsigned* __restrict__ featPk, const float* __restrict__ featCf,
    const float* __restrict__ Zp, float* __restrict__ out) {
  __shared__ __align__(16) float4 wgtS[12];
  __shared__ float tbS[12];
  __shared__ float Pr[12][32];
  __shared__ float Zl[NF * 5];
  __shared__ unsigned pkS[NF];
  __shared__ float cfS[NF];
  const int bx = blockIdx.x;
  const int b = bx / 342, j12 = bx % 342;
  const int t = threadIdx.x, d = t * 2;
  const int r0 = 12 * j12;

  if (t < NF) { pkS[t] = featPk[t]; cfS[t] = featCf[t]; }
  for (int i2 = t; i2 < NF * 5; i2 += 256) {   // sum the 38 partial Z's (L2-resident)
    const float* zp = Zp + (size_t)b * ZGRP * NF * 5 + i2;
    float a = 0.f;
#pragma unroll
    for (int gg = 0; gg < ZGRP; ++gg) a += zp[(size_t)gg * NF * 5];
    Zl[i2] = a;
  }
  if (t < 12) {
    const int row = r0 + t;
    tbS[t] = (row < N_) ? tb[b * N_ + row] : 0.f;
  }
  __syncthreads();
  if (t < 12) {                          // powers of s_i for this tile's 12 rows
    const float4 s = softmax4(tbS, r0, r0 + t, sb[0]);
    float* p = &Pr[t][0];
    float va = 1.f, vb = 1.f, vc = 1.f, vd = 1.f;
    p[0] = 1.f; p[8] = 1.f; p[16] = 1.f; p[24] = 1.f;
#pragma unroll
    for (int e = 1; e < 8; ++e) {
      va *= s.x; vb *= s.y; vc *= s.z; vd *= s.w;
      p[e] = va; p[8 + e] = vb; p[16 + e] = vc; p[24 + e] = vd;
    }
  }
  __syncthreads();
  if (t < 192) {                         // 16 lanes per row evaluate phi . Z
    const int row = t >> 4, fi = t & 15;
    float n0 = 0.f, n1 = 0.f, n2 = 0.f, n3 = 0.f, dn = 0.f;
    const float* pr = &Pr[row][0];
    for (int f = fi; f < NF; f += 16) {
      const unsigned pk = pkS[f];
      const float val = cfS[f] * pr[pk & 255] * pr[8 + ((pk >> 8) & 255)]
                                * pr[16 + ((pk >> 16) & 255)] * pr[24 + (pk >> 24)];
      const float* z = &Zl[f * 5];
      n0 += val * z[0]; n1 += val * z[1]; n2 += val * z[2]; n3 += val * z[3];
      dn += val * z[4];
    }
#pragma unroll
    for (int m = 8; m >= 1; m >>= 1) {
      n0 += __shfl_xor(n0, m); n1 += __shfl_xor(n1, m); n2 += __shfl_xor(n2, m);
      n3 += __shfl_xor(n3, m); dn += __shfl_xor(dn, m);
    }
    if (fi == 0) {
      const float inv = 1.f / dn;
      wgtS[row] = make_float4(n0 * inv, n1 * inv, n2 * inv, n3 * inv);
    }
  }
  __syncthreads();

  const __hip_bfloat16* hb = h + (size_t)b * N_ * D_;
  float2 hv[12];
#pragma unroll
  for (int q = 0; q < 12; ++q) {
    const int row = r0 + q;
    if (row < N_) {
      const ushort2 u = *(const ushort2*)(hb + (size_t)row * D_ + d);
      hv[q] = make_float2(bf2f(u.x), bf2f(u.y));
    } else {
      hv[q] = make_float2(0.f, 0.f);
    }
  }

  float2 p2[6], p3[4], p4[3];
#pragma unroll
  for (int g = 0; g < 6; ++g) {
    p2[g].x = (hv[2 * g].x + hv[2 * g + 1].x) * 0.5f;
    p2[g].y = (hv[2 * g].y + hv[2 * g + 1].y) * 0.5f;
  }
#pragma unroll
  for (int g = 0; g < 4; ++g) {
    p3[g].x = (hv[3 * g].x + hv[3 * g + 1].x + hv[3 * g + 2].x) * (1.f / 3.f);
    p3[g].y = (hv[3 * g].y + hv[3 * g + 1].y + hv[3 * g + 2].y) * (1.f / 3.f);
  }
#pragma unroll
  for (int g = 0; g < 3; ++g) {
    p4[g].x = (hv[4 * g].x + hv[4 * g + 1].x + hv[4 * g + 2].x + hv[4 * g + 3].x) * 0.25f;
    p4[g].y = (hv[4 * g].y + hv[4 * g + 1].y + hv[4 * g + 2].y + hv[4 * g + 3].y) * 0.25f;
  }

#pragma unroll
  for (int o = 0; o < 3; ++o) {
    const int orow = j12 * 3 + o;
    if (orow < 1024) {
      float ox = 0.f, oy = 0.f;
#pragma unroll
      for (int rr = 0; rr < 4; ++rr) {
        const int r = 4 * o + rr;
        const float4 wv = wgtS[r];
        const float2 p1 = hv[r];
        const float2 q2 = p2[r >> 1];
        const float2 q3 = p3[r / 3];
        const float2 q4 = p4[o];
        ox += wv.x * p1.x + wv.y * q2.x + wv.z * q3.x + wv.w * q4.x;
        oy += wv.x * p1.y + wv.y * q2.y + wv.z * q3.y + wv.w * q4.y;
      }
      float2 ov; ov.x = ox * 0.25f; ov.y = oy * 0.25f;
      *(float2*)(out + (size_t)(b * 1024 + orow) * D_ + d) = ov;
    }
  }
}

extern "C" void kernel_launch(void* const* d_in, const int* in_sizes, int n_in,
                              void* d_out, int out_size, void* d_ws, size_t ws_size,
                              hipStream_t stream) {
  const int*   x       = (const int*)d_in[0];
  const float* emb     = (const float*)d_in[1];
  const float* conv_w  = (const float*)d_in[2];
  const float* conv_b  = (const float*)d_in[3];
  const float* proj_w  = (const float*)d_in[4];
  const float* proj_b  = (const float*)d_in[5];
  const float* score_w = (const float*)d_in[6];
  const float* score_b = (const float*)d_in[7];
  float* out = (float*)d_out;

  char* ws = (char*)d_ws;
  size_t off = 0;
  float*          G    = (float*)(ws + off);          off += (size_t)4 * 256 * 512 * 4;  // 2 MB
  float*          bias = (float*)(ws + off);          off += (size_t)512 * 4;
  __hip_bfloat16* h    = (__hip_bfloat16*)(ws + off); off += (size_t)16384 * 512 * 2;    // 16 MB
  float*          tb   = (float*)(ws + off);          off += (size_t)16384 * 4;
  float*          Zp   = (float*)(ws + off);          off += (size_t)B_ * ZGRP * NF * 5 * 4; // 638 KB
  unsigned*       featPk = (unsigned*)(ws + off);     off += (size_t)NF * 4;
  float*          featCf = (float*)(ws + off);        off += (size_t)NF * 4;
  (void)in_sizes; (void)n_in; (void)out_size; (void)ws_size;

  k_g<<<129, 256, 0, stream>>>(emb, proj_w, conv_w, conv_b, proj_b, G, bias, featPk, featCf);
  k_h<<<2048, 256, 0, stream>>>(x, G, bias, score_w, (unsigned*)h, tb);
  k_zphi<<<B_ * ZGRP, 256, 0, stream>>>(tb, score_b, featPk, Zp);
  k_fuse<<<B_ * 342, 256, 0, stream>>>(h, tb, score_b, featPk, featCf, Zp, out);
}